// Round 1
// baseline (793.562 us; speedup 1.0000x reference)
//
#include <hip/hip_runtime.h>
#include <hip/hip_bf16.h>

#define NND 30000
#define NE  480000
#define FD  256
#define HD  32
#define HEADS 4
#define NLAB 6
#define NEG_SLOPE 0.2f
#define BN_EPS 1e-5f

// ---- workspace layout (offsets in 4-byte elements) ----
#define WS_FLAG      0
#define WS_BNSUM     4
#define WS_BNSQ      260
#define WS_LOSS      516
#define WS_COUNTS    520
#define WS_ZERO_ELEMS 30524
#define WS_OFFSETS   30524
#define WS_CURSOR    60528
#define WS_GAMMA     90528
#define WS_BETA      90784
#define WS_WLIN      91040
#define WS_BLIN      123808
#define WS_WGAT      123936
#define WS_ATT       156704
#define WS_BGAT      156960
#define WS_WP        157088
#define WS_BP        157600
#define WS_RW        157616
#define WS_SCALE     182192
#define WS_SHIFT     182448
#define WS_WC        182704
#define WS_BC        248240
#define WS_SD        248496
#define WS_SS        368496
#define WS_ONORM     488496
#define WS_CSR       668496
#define WS_XF        1178496
#define WS_Y         8858496
#define WS_XCG       16538496

#define OUT_LOSS_IDX 180000
#define OUT_FEAT_IDX 180001

__device__ __forceinline__ float lrelu(float a) { return a >= 0.0f ? a : NEG_SLOPE * a; }

// ---------- dtype detection: gamma is all-ones ----------
__global__ void k_detect(const unsigned int* gamma_raw, int* flag) {
    unsigned int w = gamma_raw[0];
    *flag = ((w & 0xFFFFu) == 0x3F80u) ? 1 : 0;   // bf16 pair 0x3F803F80 vs f32 0x3F800000
}

__device__ __forceinline__ float cvt_load(const void* p, int i, int f) {
    if (f) return __bfloat162float(((const __hip_bfloat16*)p)[i]);
    return ((const float*)p)[i];
}

__global__ void k_convert(const void* src, float* dst, int n, const int* flagp) {
    int f = *flagp;
    for (int i = blockIdx.x * blockDim.x + threadIdx.x; i < n; i += gridDim.x * blockDim.x)
        dst[i] = cvt_load(src, i, f);
}

// all small float params packed into ws params block
__global__ void k_convert_params(const void* p0, const void* p1, const void* p2, const void* p3,
                                 const void* p4, const void* p5, const void* p6, const void* p7,
                                 const void* p8, const void* p9, float* dst, const int* flagp) {
    int f = *flagp;
    int i = blockIdx.x * blockDim.x + threadIdx.x;
    if (i >= 91664) return;
    const void* p; int off;
    if      (i < 256)   { p = p0; off = i; }
    else if (i < 512)   { p = p1; off = i - 256; }
    else if (i < 33280) { p = p2; off = i - 512; }
    else if (i < 33408) { p = p3; off = i - 33280; }
    else if (i < 66176) { p = p4; off = i - 33408; }
    else if (i < 66432) { p = p5; off = i - 66176; }
    else if (i < 66560) { p = p6; off = i - 66432; }
    else if (i < 67072) { p = p7; off = i - 66560; }
    else if (i < 67088) { p = p8; off = i - 67072; }
    else                { p = p9; off = i - 67088; }
    dst[i] = cvt_load(p, off, f);
}

// ---------- batchnorm stats ----------
__global__ void k_bn_stats(const float* xf, float* bn_sum, float* bn_sq) {
    int t = threadIdx.x;                       // 256 threads, one feature each
    int rows = (NND + gridDim.x - 1) / gridDim.x;
    int r0 = blockIdx.x * rows;
    int r1 = min(NND, r0 + rows);
    float s = 0.0f, ss = 0.0f;
    for (int r = r0; r < r1; ++r) {
        float v = xf[(size_t)r * FD + t];
        s += v; ss += v * v;
    }
    atomicAdd(&bn_sum[t], s);
    atomicAdd(&bn_sq[t], ss);
}

__global__ void k_bn_final(const float* bn_sum, const float* bn_sq, const float* gamma,
                           const float* beta, float* scale, float* shift) {
    int t = threadIdx.x;
    float mean = bn_sum[t] / (float)NND;
    float var  = bn_sq[t] / (float)NND - mean * mean;
    float inv  = 1.0f / sqrtf(var + BN_EPS);
    float sc   = gamma[t] * inv;
    scale[t] = sc;
    shift[t] = beta[t] - mean * sc;
}

// fold BN into combined weight Wc[k][j] (j<128: lin, j>=128: gat) and bias bc
__global__ void k_fold(const float* wlin, const float* wgat, const float* blin,
                       const float* scale, const float* shift, float* Wc, float* bc) {
    int j = blockIdx.x;      // 0..255
    int k = threadIdx.x;     // 0..255
    float w = (j < 128) ? wlin[k * 128 + j] : wgat[k * 128 + (j - 128)];
    Wc[k * 256 + j] = scale[k] * w;
    __shared__ float red[256];
    red[k] = shift[k] * w;
    __syncthreads();
    for (int s = 128; s > 0; s >>= 1) { if (k < s) red[k] += red[k + s]; __syncthreads(); }
    if (k == 0) bc[j] = red[0] + (j < 128 ? blin[j] : 0.0f);
}

// ---------- GEMM: Y[N][256] = xf[N][256] @ Wc[256][256] + bc ----------
__global__ __launch_bounds__(256) void k_gemm(const float* A, const float* B,
                                              const float* bias, float* C) {
    __shared__ __align__(16) float As[16][128];
    __shared__ __align__(16) float Bs[16][64];
    int t  = threadIdx.x;
    int bm = blockIdx.x * 128;
    int bn = blockIdx.y * 64;
    int tr = t / 16, tc = t % 16;
    float acc[8][4] = {};
    int alm = t >> 2;           // 0..63
    int alk = (t & 3) * 4;      // k quad
    int blk = t >> 4;           // 0..15
    int bln = (t & 15) * 4;
    for (int k0 = 0; k0 < 256; k0 += 16) {
        #pragma unroll
        for (int half = 0; half < 2; ++half) {
            int row = bm + alm + half * 64;
            float4 av = make_float4(0.f, 0.f, 0.f, 0.f);
            if (row < NND) av = *(const float4*)(A + (size_t)row * 256 + k0 + alk);
            int m = alm + half * 64;
            As[alk + 0][m] = av.x; As[alk + 1][m] = av.y;
            As[alk + 2][m] = av.z; As[alk + 3][m] = av.w;
        }
        float4 bv = *(const float4*)(B + (size_t)(k0 + blk) * 256 + bn + bln);
        *(float4*)&Bs[blk][bln] = bv;
        __syncthreads();
        #pragma unroll
        for (int kk = 0; kk < 16; ++kk) {
            float a[8], b[4];
            *(float4*)&a[0] = *(const float4*)&As[kk][tr * 8];
            *(float4*)&a[4] = *(const float4*)&As[kk][tr * 8 + 4];
            *(float4*)&b[0] = *(const float4*)&Bs[kk][tc * 4];
            #pragma unroll
            for (int i = 0; i < 8; ++i)
                #pragma unroll
                for (int j = 0; j < 4; ++j) acc[i][j] += a[i] * b[j];
        }
        __syncthreads();
    }
    #pragma unroll
    for (int i = 0; i < 8; ++i) {
        int row = bm + tr * 8 + i;
        if (row < NND) {
            int col = bn + tc * 4;
            float4 o;
            o.x = acc[i][0] + bias[col + 0];
            o.y = acc[i][1] + bias[col + 1];
            o.z = acc[i][2] + bias[col + 2];
            o.w = acc[i][3] + bias[col + 3];
            *(float4*)(C + (size_t)row * 256 + col) = o;
        }
    }
}

// ---------- per-node attention scores ----------
__global__ void k_scores(const float* Y, const float* attf, float* sD, float* sS) {
    int idx = blockIdx.x * blockDim.x + threadIdx.x;
    if (idx >= NND * HEADS) return;
    int n = idx >> 2, h = idx & 3;
    const float* xrow = Y + (size_t)n * 256 + 128 + h * 32;
    const float* ai = attf + h * 64;
    const float* aj = ai + 32;
    float si = 0.f, sj = 0.f;
    #pragma unroll
    for (int k = 0; k < 32; ++k) { float v = xrow[k]; si += v * ai[k]; sj += v * aj[k]; }
    sD[idx] = si; sS[idx] = sj;
}

// ---------- CSR build ----------
__global__ void k_count(const int* ei, int* counts) {
    int e = blockIdx.x * blockDim.x + threadIdx.x;
    if (e >= NE + NND) return;
    int d = (e < NE) ? ei[NE + e] : (e - NE);
    atomicAdd(&counts[d], 1);
}

__global__ void k_scan(const int* counts, int* offsets, int* cursor) {
    __shared__ int sd[1024];
    __shared__ int carry;
    int t = threadIdx.x;
    if (t == 0) carry = 0;
    __syncthreads();
    for (int base = 0; base < NND; base += 1024) {
        int i = base + t;
        int v = (i < NND) ? counts[i] : 0;
        sd[t] = v;
        __syncthreads();
        for (int off = 1; off < 1024; off <<= 1) {
            int x = (t >= off) ? sd[t - off] : 0;
            __syncthreads();
            sd[t] += x;
            __syncthreads();
        }
        int excl = carry + sd[t] - v;
        if (i < NND) { offsets[i] = excl; cursor[i] = excl; }
        int tot = sd[1023];
        __syncthreads();
        if (t == 0) carry += tot;
        __syncthreads();
    }
}

__global__ void k_scatter(const int* ei, int* cursor, int* csr) {
    int e = blockIdx.x * blockDim.x + threadIdx.x;
    if (e >= NE + NND) return;
    int s, d;
    if (e < NE) { s = ei[e]; d = ei[NE + e]; } else { s = d = e - NE; }
    int pos = atomicAdd(&cursor[d], 1);
    csr[pos] = s;
}

// ---------- GAT aggregation: one wave per node ----------
__global__ __launch_bounds__(256) void k_aggr(const float* Y, const float* sD, const float* sS,
                                              const int* offsets, const int* counts, const int* csr,
                                              const float* bgat, float* xcg) {
    int wave = (blockIdx.x * blockDim.x + threadIdx.x) >> 6;
    int lane = threadIdx.x & 63;
    if (wave >= NND) return;
    int n = wave;
    int start = offsets[n], deg = counts[n];
    float4 sd = *(const float4*)(sD + (size_t)n * 4);
    // pass 1: per-head max
    float m0 = -1e30f, m1 = -1e30f, m2 = -1e30f, m3 = -1e30f;
    for (int e = lane; e < deg; e += 64) {
        int s = csr[start + e];
        float4 sj = *(const float4*)(sS + (size_t)s * 4);
        m0 = fmaxf(m0, lrelu(sd.x + sj.x));
        m1 = fmaxf(m1, lrelu(sd.y + sj.y));
        m2 = fmaxf(m2, lrelu(sd.z + sj.z));
        m3 = fmaxf(m3, lrelu(sd.w + sj.w));
    }
    #pragma unroll
    for (int off = 1; off < 64; off <<= 1) {
        m0 = fmaxf(m0, __shfl_xor(m0, off));
        m1 = fmaxf(m1, __shfl_xor(m1, off));
        m2 = fmaxf(m2, __shfl_xor(m2, off));
        m3 = fmaxf(m3, __shfl_xor(m3, off));
    }
    // pass 2: denominators
    float s0 = 0.f, s1 = 0.f, s2 = 0.f, s3 = 0.f;
    for (int e = lane; e < deg; e += 64) {
        int s = csr[start + e];
        float4 sj = *(const float4*)(sS + (size_t)s * 4);
        s0 += expf(lrelu(sd.x + sj.x) - m0);
        s1 += expf(lrelu(sd.y + sj.y) - m1);
        s2 += expf(lrelu(sd.z + sj.z) - m2);
        s3 += expf(lrelu(sd.w + sj.w) - m3);
    }
    #pragma unroll
    for (int off = 1; off < 64; off <<= 1) {
        s0 += __shfl_xor(s0, off); s1 += __shfl_xor(s1, off);
        s2 += __shfl_xor(s2, off); s3 += __shfl_xor(s3, off);
    }
    float i0 = 1.0f / (s0 + 1e-16f), i1 = 1.0f / (s1 + 1e-16f);
    float i2 = 1.0f / (s2 + 1e-16f), i3 = 1.0f / (s3 + 1e-16f);
    // pass 3: weighted gather; lane holds slots lane (h=lane>>5) and 64+lane (h=2+(lane>>5))
    float acc0 = 0.f, acc1 = 0.f;
    int hA = lane >> 5;
    for (int e = 0; e < deg; ++e) {
        int s = csr[start + e];
        float4 sj = *(const float4*)(sS + (size_t)s * 4);
        float w0 = expf(lrelu(sd.x + sj.x) - m0) * i0;
        float w1 = expf(lrelu(sd.y + sj.y) - m1) * i1;
        float w2 = expf(lrelu(sd.z + sj.z) - m2) * i2;
        float w3 = expf(lrelu(sd.w + sj.w) - m3) * i3;
        float wA = hA ? w1 : w0;
        float wB = hA ? w3 : w2;
        const float* xrow = Y + (size_t)s * 256 + 128;
        acc0 += wA * xrow[lane];
        acc1 += wB * xrow[64 + lane];
    }
    float r0 = acc0 + bgat[lane];
    float r1 = acc1 + bgat[64 + lane];
    xcg[(size_t)n * 128 + lane]      = r0 > 0.f ? r0 : 0.f;
    xcg[(size_t)n * 128 + 64 + lane] = r1 > 0.f ? r1 : 0.f;
}

// ---------- primary caps + dynamic routing: 192 threads = (c=6, o=32) ----------
__global__ __launch_bounds__(192) void k_route(const float* Y, const float* xcg,
                                               const float* Wpf, const float* bpf, const float* rwf,
                                               float* onorm, void* dout, const int* flagp) {
    int flag = *flagp;
    int t = threadIdx.x;
    int c = t >> 5;      // 0..5
    int o = t & 31;
    __shared__ float lds_wp[512];
    __shared__ float lds_bp[16];
    __shared__ float lds_xc[256];
    __shared__ float lds_u[128];
    if (t < 16) lds_bp[t] = bpf[t];
    for (int i = t; i < 512; i += 192) lds_wp[i] = Wpf[i];
    // per-thread route_w slice: rw[c][r][i][o], 128 regs
    float rwr[128];
    #pragma unroll
    for (int r = 0; r < 16; ++r)
        #pragma unroll
        for (int i = 0; i < 8; ++i)
            rwr[r * 8 + i] = rwf[((c * 16 + r) * 8 + i) * 32 + o];
    __syncthreads();
    float* outf = (float*)dout;
    __hip_bfloat16* outb = (__hip_bfloat16*)dout;
    for (int n = blockIdx.x; n < NND; n += gridDim.x) {
        if (t < 128) {
            lds_xc[t] = xcg[(size_t)n * 128 + t];                 // gat heads (already relu'd)
            float h = Y[(size_t)n * 256 + t];                     // hidden heads
            lds_xc[128 + t] = h > 0.f ? h : 0.f;
        }
        __syncthreads();
        if (t < 128) {   // pc[c2][r8][o8] + squash over o8 -> u
            int cc = t >> 6, r = (t >> 3) & 7, oo = t & 7;
            float pc = lds_bp[cc * 8 + oo];
            #pragma unroll
            for (int k = 0; k < 32; ++k)
                pc += lds_xc[r * 32 + k] * lds_wp[cc * 256 + k * 8 + oo];
            float sq = pc * pc;
            sq += __shfl_xor(sq, 1); sq += __shfl_xor(sq, 2); sq += __shfl_xor(sq, 4);
            float coeff = sq / ((1.0f + sq) * sqrtf(sq));
            lds_u[(cc * 8 + r) * 8 + oo] = pc * coeff;
        }
        __syncthreads();
        float prior[16];
        #pragma unroll
        for (int r = 0; r < 16; ++r) {
            float p = 0.f;
            #pragma unroll
            for (int i = 0; i < 8; ++i) p += lds_u[r * 8 + i] * rwr[r * 8 + i];
            prior[r] = p;
        }
        float logits[16];
        #pragma unroll
        for (int r = 0; r < 16; ++r) logits[r] = 0.f;
        float v = 0.f, sqv = 0.f;
        #pragma unroll
        for (int it = 0; it < 3; ++it) {
            float mx = logits[0];
            #pragma unroll
            for (int r = 1; r < 16; ++r) mx = fmaxf(mx, logits[r]);
            float pr[16]; float sum = 0.f;
            #pragma unroll
            for (int r = 0; r < 16; ++r) { pr[r] = expf(logits[r] - mx); sum += pr[r]; }
            float isum = 1.0f / sum;
            float s = 0.f;
            #pragma unroll
            for (int r = 0; r < 16; ++r) s += pr[r] * isum * prior[r];
            float sq = s * s;
            sq += __shfl_xor(sq, 1); sq += __shfl_xor(sq, 2); sq += __shfl_xor(sq, 4);
            sq += __shfl_xor(sq, 8); sq += __shfl_xor(sq, 16);
            float coeff = sq / ((1.0f + sq) * sqrtf(sq));
            v = s * coeff; sqv = sq;
            if (it < 2) {
                #pragma unroll
                for (int r = 0; r < 16; ++r) {
                    float d = prior[r] * v;
                    d += __shfl_xor(d, 1); d += __shfl_xor(d, 2); d += __shfl_xor(d, 4);
                    d += __shfl_xor(d, 8); d += __shfl_xor(d, 16);
                    logits[r] += d;
                }
            }
        }
        float norm = sqv / (1.0f + sqv);      // ||squash(s)|| = sq/(1+sq)
        size_t fidx = (size_t)OUT_FEAT_IDX + (size_t)n * 192 + c * 32 + o;
        if (flag) outb[fidx] = __float2bfloat16(v); else outf[fidx] = v;
        if (o == 0) {
            onorm[n * 6 + c] = norm;
            size_t oidx = (size_t)n * 6 + c;
            if (flag) outb[oidx] = __float2bfloat16(norm); else outf[oidx] = norm;
        }
        __syncthreads();
    }
}

// ---------- loss ----------
__global__ void k_loss(const float* onorm, const int* y, float* acc) {
    float l = 0.f;
    for (int n = blockIdx.x * blockDim.x + threadIdx.x; n < NND; n += gridDim.x * blockDim.x) {
        const float* v = onorm + n * 6;
        float m = v[0];
        #pragma unroll
        for (int cc = 1; cc < 6; ++cc) m = fmaxf(m, v[cc]);
        float s = 0.f;
        #pragma unroll
        for (int cc = 0; cc < 6; ++cc) s += expf(v[cc] - m);
        l += m + logf(s) - v[y[n]];
    }
    __shared__ float red[256];
    red[threadIdx.x] = l;
    __syncthreads();
    for (int s = 128; s > 0; s >>= 1) { if (threadIdx.x < s) red[threadIdx.x] += red[threadIdx.x + s]; __syncthreads(); }
    if (threadIdx.x == 0) atomicAdd(acc, red[0]);
}

__global__ void k_loss_fin(const float* acc, void* dout, const int* flagp) {
    float v = acc[0] / (float)NND;
    if (*flagp) ((__hip_bfloat16*)dout)[OUT_LOSS_IDX] = __float2bfloat16(v);
    else        ((float*)dout)[OUT_LOSS_IDX] = v;
}

extern "C" void kernel_launch(void* const* d_in, const int* in_sizes, int n_in,
                              void* d_out, int out_size, void* d_ws, size_t ws_size,
                              hipStream_t stream) {
    (void)in_sizes; (void)n_in; (void)out_size; (void)ws_size;
    float* ws = (float*)d_ws;
    int*  wsi = (int*)d_ws;
    const int* ei = (const int*)d_in[11];
    const int* y  = (const int*)d_in[12];

    hipMemsetAsync(d_ws, 0, (size_t)WS_ZERO_ELEMS * 4, stream);
    k_detect<<<1, 1, 0, stream>>>((const unsigned int*)d_in[1], wsi + WS_FLAG);

    k_convert<<<2048, 256, 0, stream>>>(d_in[0], ws + WS_XF, NND * FD, wsi + WS_FLAG);
    k_convert_params<<<(91664 + 255) / 256, 256, 0, stream>>>(
        d_in[1], d_in[2], d_in[3], d_in[4], d_in[5], d_in[6], d_in[7], d_in[8], d_in[9], d_in[10],
        ws + WS_GAMMA, wsi + WS_FLAG);

    k_bn_stats<<<120, 256, 0, stream>>>(ws + WS_XF, ws + WS_BNSUM, ws + WS_BNSQ);
    k_bn_final<<<1, 256, 0, stream>>>(ws + WS_BNSUM, ws + WS_BNSQ, ws + WS_GAMMA, ws + WS_BETA,
                                      ws + WS_SCALE, ws + WS_SHIFT);
    k_fold<<<256, 256, 0, stream>>>(ws + WS_WLIN, ws + WS_WGAT, ws + WS_BLIN,
                                    ws + WS_SCALE, ws + WS_SHIFT, ws + WS_WC, ws + WS_BC);

    k_gemm<<<dim3((NND + 127) / 128, 4), 256, 0, stream>>>(ws + WS_XF, ws + WS_WC, ws + WS_BC, ws + WS_Y);

    k_scores<<<(NND * HEADS + 255) / 256, 256, 0, stream>>>(ws + WS_Y, ws + WS_ATT, ws + WS_SD, ws + WS_SS);

    k_count<<<(NE + NND + 255) / 256, 256, 0, stream>>>(ei, wsi + WS_COUNTS);
    k_scan<<<1, 1024, 0, stream>>>(wsi + WS_COUNTS, wsi + WS_OFFSETS, wsi + WS_CURSOR);
    k_scatter<<<(NE + NND + 255) / 256, 256, 0, stream>>>(ei, wsi + WS_CURSOR, wsi + WS_CSR);

    k_aggr<<<(NND + 3) / 4, 256, 0, stream>>>(ws + WS_Y, ws + WS_SD, ws + WS_SS,
                                              wsi + WS_OFFSETS, wsi + WS_COUNTS, wsi + WS_CSR,
                                              ws + WS_BGAT, ws + WS_XCG);

    k_route<<<2500, 192, 0, stream>>>(ws + WS_Y, ws + WS_XCG, ws + WS_WP, ws + WS_BP, ws + WS_RW,
                                      ws + WS_ONORM, d_out, wsi + WS_FLAG);

    k_loss<<<118, 256, 0, stream>>>(ws + WS_ONORM, y, ws + WS_LOSS);
    k_loss_fin<<<1, 1, 0, stream>>>(ws + WS_LOSS, d_out, wsi + WS_FLAG);
}

// Round 2
// 691.448 us; speedup vs baseline: 1.1477x; 1.1477x over previous
//
#include <hip/hip_runtime.h>
#include <hip/hip_bf16.h>

#define NND 30000
#define NE  480000
#define FD  256
#define HD  32
#define HEADS 4
#define NLAB 6
#define NEG_SLOPE 0.2f
#define BN_EPS 1e-5f

// ---- workspace layout (offsets in 4-byte elements) ----
#define WS_FLAG      0
#define WS_BNSUM     4
#define WS_BNSQ      260
#define WS_LOSS      516
#define WS_COUNTS    520
#define WS_ZERO_ELEMS 30524
#define WS_OFFSETS   30524
#define WS_CURSOR    60528
#define WS_GAMMA     90528
#define WS_BETA      90784
#define WS_WLIN      91040
#define WS_BLIN      123808
#define WS_WGAT      123936
#define WS_ATT       156704
#define WS_BGAT      156960
#define WS_WP        157088
#define WS_BP        157600
#define WS_RW        157616
#define WS_SCALE     182192
#define WS_SHIFT     182448
#define WS_WC        182704
#define WS_BC        248240
#define WS_SD        248496
#define WS_SS        368496
#define WS_ONORM     488496
#define WS_CSR       668496
#define WS_XF        1178496
// U reuses the XF region (XF dead after k_gemm; U written after k_aggr)
#define WS_U         1178496
#define WS_BLKSUM    5018496
#define WS_BLKOFF    5018624
#define WS_Y         8858496
#define WS_XCG       16538496

#define OUT_LOSS_IDX 180000
#define OUT_FEAT_IDX 180001

#define SCAN_NB 118   // ceil(30000/256)

__device__ __forceinline__ float lrelu(float a) { return a >= 0.0f ? a : NEG_SLOPE * a; }

// ---------- dtype detection: gamma is all-ones ----------
__global__ void k_detect(const unsigned int* gamma_raw, int* flag) {
    unsigned int w = gamma_raw[0];
    *flag = ((w & 0xFFFFu) == 0x3F80u) ? 1 : 0;   // bf16 pair 0x3F803F80 vs f32 0x3F800000
}

__device__ __forceinline__ float cvt_load(const void* p, int i, int f) {
    if (f) return __bfloat162float(((const __hip_bfloat16*)p)[i]);
    return ((const float*)p)[i];
}

__global__ void k_convert(const void* src, float* dst, int n, const int* flagp) {
    int f = *flagp;
    for (int i = blockIdx.x * blockDim.x + threadIdx.x; i < n; i += gridDim.x * blockDim.x)
        dst[i] = cvt_load(src, i, f);
}

// all small float params packed into ws params block
__global__ void k_convert_params(const void* p0, const void* p1, const void* p2, const void* p3,
                                 const void* p4, const void* p5, const void* p6, const void* p7,
                                 const void* p8, const void* p9, float* dst, const int* flagp) {
    int f = *flagp;
    int i = blockIdx.x * blockDim.x + threadIdx.x;
    if (i >= 91664) return;
    const void* p; int off;
    if      (i < 256)   { p = p0; off = i; }
    else if (i < 512)   { p = p1; off = i - 256; }
    else if (i < 33280) { p = p2; off = i - 512; }
    else if (i < 33408) { p = p3; off = i - 33280; }
    else if (i < 66176) { p = p4; off = i - 33408; }
    else if (i < 66432) { p = p5; off = i - 66176; }
    else if (i < 66560) { p = p6; off = i - 66432; }
    else if (i < 67072) { p = p7; off = i - 66560; }
    else if (i < 67088) { p = p8; off = i - 67072; }
    else                { p = p9; off = i - 67088; }
    dst[i] = cvt_load(p, off, f);
}

// ---------- batchnorm stats ----------
__global__ void k_bn_stats(const float* xf, float* bn_sum, float* bn_sq) {
    int t = threadIdx.x;                       // 256 threads, one feature each
    int rows = (NND + gridDim.x - 1) / gridDim.x;
    int r0 = blockIdx.x * rows;
    int r1 = min(NND, r0 + rows);
    float s = 0.0f, ss = 0.0f;
    for (int r = r0; r < r1; ++r) {
        float v = xf[(size_t)r * FD + t];
        s += v; ss += v * v;
    }
    atomicAdd(&bn_sum[t], s);
    atomicAdd(&bn_sq[t], ss);
}

__global__ void k_bn_final(const float* bn_sum, const float* bn_sq, const float* gamma,
                           const float* beta, float* scale, float* shift) {
    int t = threadIdx.x;
    float mean = bn_sum[t] / (float)NND;
    float var  = bn_sq[t] / (float)NND - mean * mean;
    float inv  = 1.0f / sqrtf(var + BN_EPS);
    float sc   = gamma[t] * inv;
    scale[t] = sc;
    shift[t] = beta[t] - mean * sc;
}

// fold BN into combined weight Wc[k][j] (j<128: lin, j>=128: gat) and bias bc
__global__ void k_fold(const float* wlin, const float* wgat, const float* blin,
                       const float* scale, const float* shift, float* Wc, float* bc) {
    int j = blockIdx.x;      // 0..255
    int k = threadIdx.x;     // 0..255
    float w = (j < 128) ? wlin[k * 128 + j] : wgat[k * 128 + (j - 128)];
    Wc[k * 256 + j] = scale[k] * w;
    __shared__ float red[256];
    red[k] = shift[k] * w;
    __syncthreads();
    for (int s = 128; s > 0; s >>= 1) { if (k < s) red[k] += red[k + s]; __syncthreads(); }
    if (k == 0) bc[j] = red[0] + (j < 128 ? blin[j] : 0.0f);
}

// ---------- GEMM: Y[N][256] = xf[N][256] @ Wc[256][256] + bc ----------
__global__ __launch_bounds__(256) void k_gemm(const float* A, const float* B,
                                              const float* bias, float* C) {
    __shared__ __align__(16) float As[16][128];
    __shared__ __align__(16) float Bs[16][64];
    int t  = threadIdx.x;
    int bm = blockIdx.x * 128;
    int bn = blockIdx.y * 64;
    int tr = t / 16, tc = t % 16;
    float acc[8][4] = {};
    int alm = t >> 2;           // 0..63
    int alk = (t & 3) * 4;      // k quad
    int blk = t >> 4;           // 0..15
    int bln = (t & 15) * 4;
    for (int k0 = 0; k0 < 256; k0 += 16) {
        #pragma unroll
        for (int half = 0; half < 2; ++half) {
            int row = bm + alm + half * 64;
            float4 av = make_float4(0.f, 0.f, 0.f, 0.f);
            if (row < NND) av = *(const float4*)(A + (size_t)row * 256 + k0 + alk);
            int m = alm + half * 64;
            As[alk + 0][m] = av.x; As[alk + 1][m] = av.y;
            As[alk + 2][m] = av.z; As[alk + 3][m] = av.w;
        }
        float4 bv = *(const float4*)(B + (size_t)(k0 + blk) * 256 + bn + bln);
        *(float4*)&Bs[blk][bln] = bv;
        __syncthreads();
        #pragma unroll
        for (int kk = 0; kk < 16; ++kk) {
            float a[8], b[4];
            *(float4*)&a[0] = *(const float4*)&As[kk][tr * 8];
            *(float4*)&a[4] = *(const float4*)&As[kk][tr * 8 + 4];
            *(float4*)&b[0] = *(const float4*)&Bs[kk][tc * 4];
            #pragma unroll
            for (int i = 0; i < 8; ++i)
                #pragma unroll
                for (int j = 0; j < 4; ++j) acc[i][j] += a[i] * b[j];
        }
        __syncthreads();
    }
    #pragma unroll
    for (int i = 0; i < 8; ++i) {
        int row = bm + tr * 8 + i;
        if (row < NND) {
            int col = bn + tc * 4;
            float4 o;
            o.x = acc[i][0] + bias[col + 0];
            o.y = acc[i][1] + bias[col + 1];
            o.z = acc[i][2] + bias[col + 2];
            o.w = acc[i][3] + bias[col + 3];
            *(float4*)(C + (size_t)row * 256 + col) = o;
        }
    }
}

// ---------- per-node attention scores ----------
__global__ void k_scores(const float* Y, const float* attf, float* sD, float* sS) {
    int idx = blockIdx.x * blockDim.x + threadIdx.x;
    if (idx >= NND * HEADS) return;
    int n = idx >> 2, h = idx & 3;
    const float* xrow = Y + (size_t)n * 256 + 128 + h * 32;
    const float* ai = attf + h * 64;
    const float* aj = ai + 32;
    float si = 0.f, sj = 0.f;
    #pragma unroll
    for (int k = 0; k < 32; ++k) { float v = xrow[k]; si += v * ai[k]; sj += v * aj[k]; }
    sD[idx] = si; sS[idx] = sj;
}

// ---------- CSR build ----------
__global__ void k_count(const int* ei, int* counts) {
    int e = blockIdx.x * blockDim.x + threadIdx.x;
    if (e >= NE + NND) return;
    int d = (e < NE) ? ei[NE + e] : (e - NE);
    atomicAdd(&counts[d], 1);
}

// hierarchical scan: block-local
__global__ void k_scan_blk(const int* counts, int* offsets, int* blksum) {
    int t = threadIdx.x, b = blockIdx.x;
    int i = b * 256 + t;
    int v = (i < NND) ? counts[i] : 0;
    int lane = t & 63, wv = t >> 6;
    int x = v;
    #pragma unroll
    for (int off = 1; off < 64; off <<= 1) {
        int y = __shfl_up(x, off);
        if (lane >= off) x += y;
    }
    __shared__ int wsum[4];
    if (lane == 63) wsum[wv] = x;
    __syncthreads();
    int add = 0;
    #pragma unroll
    for (int w = 0; w < 4; ++w) add += (w < wv) ? wsum[w] : 0;
    if (i < NND) offsets[i] = add + x - v;     // block-local exclusive
    if (t == 255) blksum[b] = add + x;
}

__global__ void k_scan_top(const int* blksum, int* blkoff) {
    int t = threadIdx.x;   // 128 threads, 2 waves
    int v = (t < SCAN_NB) ? blksum[t] : 0;
    int lane = t & 63, wv = t >> 6;
    int x = v;
    #pragma unroll
    for (int off = 1; off < 64; off <<= 1) {
        int y = __shfl_up(x, off);
        if (lane >= off) x += y;
    }
    __shared__ int ws2[2];
    if (lane == 63) ws2[wv] = x;
    __syncthreads();
    int add = (wv == 1) ? ws2[0] : 0;
    if (t < SCAN_NB) blkoff[t] = add + x - v;
}

__global__ void k_scan_add(const int* blkoff, int* offsets, int* cursor) {
    int i = blockIdx.x * 256 + threadIdx.x;
    if (i >= NND) return;
    int o = offsets[i] + blkoff[blockIdx.x];
    offsets[i] = o;
    cursor[i] = o;
}

__global__ void k_scatter(const int* ei, int* cursor, int* csr) {
    int e = blockIdx.x * blockDim.x + threadIdx.x;
    if (e >= NE + NND) return;
    int s, d;
    if (e < NE) { s = ei[e]; d = ei[NE + e]; } else { s = d = e - NE; }
    int pos = atomicAdd(&cursor[d], 1);
    csr[pos] = s;
}

// ---------- GAT aggregation: one wave per node ----------
__global__ __launch_bounds__(256) void k_aggr(const float* Y, const float* sD, const float* sS,
                                              const int* offsets, const int* counts, const int* csr,
                                              const float* bgat, float* xcg) {
    int wave = (blockIdx.x * blockDim.x + threadIdx.x) >> 6;
    int lane = threadIdx.x & 63;
    if (wave >= NND) return;
    int n = wave;
    int start = offsets[n], deg = counts[n];
    float4 sd = *(const float4*)(sD + (size_t)n * 4);
    // pass 1: per-head max
    float m0 = -1e30f, m1 = -1e30f, m2 = -1e30f, m3 = -1e30f;
    for (int e = lane; e < deg; e += 64) {
        int s = csr[start + e];
        float4 sj = *(const float4*)(sS + (size_t)s * 4);
        m0 = fmaxf(m0, lrelu(sd.x + sj.x));
        m1 = fmaxf(m1, lrelu(sd.y + sj.y));
        m2 = fmaxf(m2, lrelu(sd.z + sj.z));
        m3 = fmaxf(m3, lrelu(sd.w + sj.w));
    }
    #pragma unroll
    for (int off = 1; off < 64; off <<= 1) {
        m0 = fmaxf(m0, __shfl_xor(m0, off));
        m1 = fmaxf(m1, __shfl_xor(m1, off));
        m2 = fmaxf(m2, __shfl_xor(m2, off));
        m3 = fmaxf(m3, __shfl_xor(m3, off));
    }
    // pass 2: denominators
    float s0 = 0.f, s1 = 0.f, s2 = 0.f, s3 = 0.f;
    for (int e = lane; e < deg; e += 64) {
        int s = csr[start + e];
        float4 sj = *(const float4*)(sS + (size_t)s * 4);
        s0 += expf(lrelu(sd.x + sj.x) - m0);
        s1 += expf(lrelu(sd.y + sj.y) - m1);
        s2 += expf(lrelu(sd.z + sj.z) - m2);
        s3 += expf(lrelu(sd.w + sj.w) - m3);
    }
    #pragma unroll
    for (int off = 1; off < 64; off <<= 1) {
        s0 += __shfl_xor(s0, off); s1 += __shfl_xor(s1, off);
        s2 += __shfl_xor(s2, off); s3 += __shfl_xor(s3, off);
    }
    float i0 = 1.0f / (s0 + 1e-16f), i1 = 1.0f / (s1 + 1e-16f);
    float i2 = 1.0f / (s2 + 1e-16f), i3 = 1.0f / (s3 + 1e-16f);
    // pass 3: weighted gather; lane holds slots lane (h=lane>>5) and 64+lane (h=2+(lane>>5))
    float acc0 = 0.f, acc1 = 0.f;
    int hA = lane >> 5;
    for (int e = 0; e < deg; ++e) {
        int s = csr[start + e];
        float4 sj = *(const float4*)(sS + (size_t)s * 4);
        float w0 = expf(lrelu(sd.x + sj.x) - m0) * i0;
        float w1 = expf(lrelu(sd.y + sj.y) - m1) * i1;
        float w2 = expf(lrelu(sd.z + sj.z) - m2) * i2;
        float w3 = expf(lrelu(sd.w + sj.w) - m3) * i3;
        float wA = hA ? w1 : w0;
        float wB = hA ? w3 : w2;
        const float* xrow = Y + (size_t)s * 256 + 128;
        acc0 += wA * xrow[lane];
        acc1 += wB * xrow[64 + lane];
    }
    float r0 = acc0 + bgat[lane];
    float r1 = acc1 + bgat[64 + lane];
    xcg[(size_t)n * 128 + lane]      = r0 > 0.f ? r0 : 0.f;
    xcg[(size_t)n * 128 + 64 + lane] = r1 > 0.f ? r1 : 0.f;
}

// ---------- primary caps: u[n][128], one wave per node, barrier-free ----------
// lane l: r = l>>3 (0..7), oo = l&7. Computes pc[cc=0][r][oo] and pc[cc=1][r][oo].
__global__ __launch_bounds__(256, 4) void k_u(const float* Y, const float* xcg,
                                              const float* Wpf, const float* bpf, float* uG) {
    int lane = threadIdx.x & 63;
    int gw = blockIdx.x * 4 + (threadIdx.x >> 6);
    int nwaves = gridDim.x * 4;
    int r = lane >> 3, oo = lane & 7;
    // persistent Wp slice: wp[cc][k][oo], k=0..31
    float wpA[32], wpB[32];
    #pragma unroll
    for (int k = 0; k < 32; ++k) {
        wpA[k] = Wpf[k * 8 + oo];
        wpB[k] = Wpf[256 + k * 8 + oo];
    }
    float bpA = bpf[oo], bpB = bpf[8 + oo];
    for (int n = gw; n < NND; n += nwaves) {
        // xc row for this r: r<4 -> gat (already relu'd), r>=4 -> hidden (relu here).
        // gat entries are >=0 so fmaxf(x,0) is a no-op there -> apply uniformly.
        const float* rowp = (r < 4) ? (xcg + (size_t)n * 128 + r * 32)
                                    : (Y + (size_t)n * 256 + (r - 4) * 32);
        float pcA = bpA, pcB = bpB;
        #pragma unroll
        for (int k4 = 0; k4 < 8; ++k4) {
            float4 xv = *(const float4*)(rowp + k4 * 4);
            xv.x = fmaxf(xv.x, 0.f); xv.y = fmaxf(xv.y, 0.f);
            xv.z = fmaxf(xv.z, 0.f); xv.w = fmaxf(xv.w, 0.f);
            pcA += xv.x * wpA[k4*4+0] + xv.y * wpA[k4*4+1] + xv.z * wpA[k4*4+2] + xv.w * wpA[k4*4+3];
            pcB += xv.x * wpB[k4*4+0] + xv.y * wpB[k4*4+1] + xv.z * wpB[k4*4+2] + xv.w * wpB[k4*4+3];
        }
        // squash over oo-group (8 lanes)
        float sA = pcA * pcA, sB = pcB * pcB;
        sA += __shfl_xor(sA, 1); sA += __shfl_xor(sA, 2); sA += __shfl_xor(sA, 4);
        sB += __shfl_xor(sB, 1); sB += __shfl_xor(sB, 2); sB += __shfl_xor(sB, 4);
        float cA = sqrtf(sA) / (1.0f + sA);
        float cB = sqrtf(sB) / (1.0f + sB);
        uG[(size_t)n * 128 + lane]      = pcA * cA;   // flat idx cc*64 + r*8 + oo = lane
        uG[(size_t)n * 128 + 64 + lane] = pcB * cB;
    }
}

// ---------- dynamic routing: one wave per (node, c), barrier-free ----------
// lane = (h = lane>>5, o = lane&31); lane holds priors[r = h*8+j][o], j=0..7.
__global__ __launch_bounds__(256, 4) void k_route2(const float* uG, const float* rwf,
                                                   float* onorm, void* dout, const int* flagp) {
    int flag = *flagp;
    int lane = threadIdx.x & 63;
    int gw = blockIdx.x * 4 + (threadIdx.x >> 6);
    int c = gw % 6;
    int widx = gw / 6;
    int nstep = (gridDim.x * 4) / 6;
    int h = lane >> 5, o = lane & 31;
    // persistent route_w slice: rw[c][h*8+j][i][o]
    float rw[8][8];
    #pragma unroll
    for (int j = 0; j < 8; ++j)
        #pragma unroll
        for (int i = 0; i < 8; ++i)
            rw[j][i] = rwf[(((c * 16) + (h * 8 + j)) * 8 + i) * 32 + o];
    float* outf = (float*)dout;
    __hip_bfloat16* outb = (__hip_bfloat16*)dout;
    for (int n = widx; n < NND; n += nstep) {
        // priors: p[j] = sum_i u[n][h*8+j][i] * rw[j][i]
        const float* up = uG + (size_t)n * 128 + h * 64;
        float p[8];
        #pragma unroll
        for (int j = 0; j < 8; ++j) {
            float4 a = *(const float4*)(up + j * 8);
            float4 b = *(const float4*)(up + j * 8 + 4);
            p[j] = a.x*rw[j][0] + a.y*rw[j][1] + a.z*rw[j][2] + a.w*rw[j][3]
                 + b.x*rw[j][4] + b.y*rw[j][5] + b.z*rw[j][6] + b.w*rw[j][7];
        }
        // ---- iter 1: probs = 1/16 exactly ----
        float tl = p[0]+p[1]+p[2]+p[3]+p[4]+p[5]+p[6]+p[7];
        float s = (tl + __shfl_xor(tl, 32)) * 0.0625f;
        float sq = s * s;
        sq += __shfl_xor(sq, 1); sq += __shfl_xor(sq, 2); sq += __shfl_xor(sq, 4);
        sq += __shfl_xor(sq, 8); sq += __shfl_xor(sq, 16);
        float v = s * (sqrtf(sq) / (1.0f + sq));
        float logits[8];
        #pragma unroll
        for (int j = 0; j < 8; ++j) {
            float d = p[j] * v;
            d += __shfl_xor(d, 1); d += __shfl_xor(d, 2); d += __shfl_xor(d, 4);
            d += __shfl_xor(d, 8); d += __shfl_xor(d, 16);
            logits[j] = d;
        }
        // ---- iters 2,3 ----
        float sq3 = 0.f, v3 = 0.f;
        #pragma unroll
        for (int it = 0; it < 2; ++it) {
            float mx = logits[0];
            #pragma unroll
            for (int j = 1; j < 8; ++j) mx = fmaxf(mx, logits[j]);
            mx = fmaxf(mx, __shfl_xor(mx, 32));
            float e[8]; float se = 0.f;
            #pragma unroll
            for (int j = 0; j < 8; ++j) { e[j] = __expf(logits[j] - mx); se += e[j]; }
            se += __shfl_xor(se, 32);
            float inv = 1.0f / se;
            float sl = 0.f;
            #pragma unroll
            for (int j = 0; j < 8; ++j) sl += e[j] * p[j];
            sl *= inv;
            float ss = sl + __shfl_xor(sl, 32);
            float q = ss * ss;
            q += __shfl_xor(q, 1); q += __shfl_xor(q, 2); q += __shfl_xor(q, 4);
            q += __shfl_xor(q, 8); q += __shfl_xor(q, 16);
            float vv = ss * (sqrtf(q) / (1.0f + q));
            if (it == 0) {
                #pragma unroll
                for (int j = 0; j < 8; ++j) {
                    float d = p[j] * vv;
                    d += __shfl_xor(d, 1); d += __shfl_xor(d, 2); d += __shfl_xor(d, 4);
                    d += __shfl_xor(d, 8); d += __shfl_xor(d, 16);
                    logits[j] += d;
                }
            } else { v3 = vv; sq3 = q; }
        }
        // ---- output ----
        if (lane < 32) {
            size_t fidx = (size_t)OUT_FEAT_IDX + (size_t)n * 192 + c * 32 + o;
            if (flag) outb[fidx] = __float2bfloat16(v3); else outf[fidx] = v3;
            if (lane == 0) {
                float norm = sq3 / (1.0f + sq3);
                onorm[n * 6 + c] = norm;
                size_t oidx = (size_t)n * 6 + c;
                if (flag) outb[oidx] = __float2bfloat16(norm); else outf[oidx] = norm;
            }
        }
    }
}

// ---------- loss ----------
__global__ void k_loss(const float* onorm, const int* y, float* acc) {
    float l = 0.f;
    for (int n = blockIdx.x * blockDim.x + threadIdx.x; n < NND; n += gridDim.x * blockDim.x) {
        const float* v = onorm + n * 6;
        float m = v[0];
        #pragma unroll
        for (int cc = 1; cc < 6; ++cc) m = fmaxf(m, v[cc]);
        float s = 0.f;
        #pragma unroll
        for (int cc = 0; cc < 6; ++cc) s += expf(v[cc] - m);
        l += m + logf(s) - v[y[n]];
    }
    __shared__ float red[256];
    red[threadIdx.x] = l;
    __syncthreads();
    for (int s = 128; s > 0; s >>= 1) { if (threadIdx.x < s) red[threadIdx.x] += red[threadIdx.x + s]; __syncthreads(); }
    if (threadIdx.x == 0) atomicAdd(acc, red[0]);
}

__global__ void k_loss_fin(const float* acc, void* dout, const int* flagp) {
    float v = acc[0] / (float)NND;
    if (*flagp) ((__hip_bfloat16*)dout)[OUT_LOSS_IDX] = __float2bfloat16(v);
    else        ((float*)dout)[OUT_LOSS_IDX] = v;
}

extern "C" void kernel_launch(void* const* d_in, const int* in_sizes, int n_in,
                              void* d_out, int out_size, void* d_ws, size_t ws_size,
                              hipStream_t stream) {
    (void)in_sizes; (void)n_in; (void)out_size; (void)ws_size;
    float* ws = (float*)d_ws;
    int*  wsi = (int*)d_ws;
    const int* ei = (const int*)d_in[11];
    const int* y  = (const int*)d_in[12];

    hipMemsetAsync(d_ws, 0, (size_t)WS_ZERO_ELEMS * 4, stream);
    k_detect<<<1, 1, 0, stream>>>((const unsigned int*)d_in[1], wsi + WS_FLAG);

    k_convert<<<2048, 256, 0, stream>>>(d_in[0], ws + WS_XF, NND * FD, wsi + WS_FLAG);
    k_convert_params<<<(91664 + 255) / 256, 256, 0, stream>>>(
        d_in[1], d_in[2], d_in[3], d_in[4], d_in[5], d_in[6], d_in[7], d_in[8], d_in[9], d_in[10],
        ws + WS_GAMMA, wsi + WS_FLAG);

    k_bn_stats<<<120, 256, 0, stream>>>(ws + WS_XF, ws + WS_BNSUM, ws + WS_BNSQ);
    k_bn_final<<<1, 256, 0, stream>>>(ws + WS_BNSUM, ws + WS_BNSQ, ws + WS_GAMMA, ws + WS_BETA,
                                      ws + WS_SCALE, ws + WS_SHIFT);
    k_fold<<<256, 256, 0, stream>>>(ws + WS_WLIN, ws + WS_WGAT, ws + WS_BLIN,
                                    ws + WS_SCALE, ws + WS_SHIFT, ws + WS_WC, ws + WS_BC);

    k_gemm<<<dim3((NND + 127) / 128, 4), 256, 0, stream>>>(ws + WS_XF, ws + WS_WC, ws + WS_BC, ws + WS_Y);

    k_scores<<<(NND * HEADS + 255) / 256, 256, 0, stream>>>(ws + WS_Y, ws + WS_ATT, ws + WS_SD, ws + WS_SS);

    k_count<<<(NE + NND + 255) / 256, 256, 0, stream>>>(ei, wsi + WS_COUNTS);
    k_scan_blk<<<SCAN_NB, 256, 0, stream>>>(wsi + WS_COUNTS, wsi + WS_OFFSETS, wsi + WS_BLKSUM);
    k_scan_top<<<1, 128, 0, stream>>>(wsi + WS_BLKSUM, wsi + WS_BLKOFF);
    k_scan_add<<<SCAN_NB, 256, 0, stream>>>(wsi + WS_BLKOFF, wsi + WS_OFFSETS, wsi + WS_CURSOR);
    k_scatter<<<(NE + NND + 255) / 256, 256, 0, stream>>>(ei, wsi + WS_CURSOR, wsi + WS_CSR);

    k_aggr<<<(NND + 3) / 4, 256, 0, stream>>>(ws + WS_Y, ws + WS_SD, ws + WS_SS,
                                              wsi + WS_OFFSETS, wsi + WS_COUNTS, wsi + WS_CSR,
                                              ws + WS_BGAT, ws + WS_XCG);

    k_u<<<512, 256, 0, stream>>>(ws + WS_Y, ws + WS_XCG, ws + WS_WP, ws + WS_BP, ws + WS_U);
    k_route2<<<768, 256, 0, stream>>>(ws + WS_U, ws + WS_RW, ws + WS_ONORM, d_out, wsi + WS_FLAG);

    k_loss<<<118, 256, 0, stream>>>(ws + WS_ONORM, y, ws + WS_LOSS);
    k_loss_fin<<<1, 1, 0, stream>>>(ws + WS_LOSS, d_out, wsi + WS_FLAG);
}

// Round 3
// 553.398 us; speedup vs baseline: 1.4340x; 1.2495x over previous
//
#include <hip/hip_runtime.h>
#include <hip/hip_bf16.h>

#define NND 30000
#define NE  480000
#define FD  256
#define HD  32
#define HEADS 4
#define NLAB 6
#define NEG_SLOPE 0.2f
#define BN_EPS 1e-5f

// ---- workspace layout (offsets in 4-byte elements) ----
#define WS_FLAG      0
#define WS_BNSUM     4
#define WS_BNSQ      260
#define WS_LOSS      516
#define WS_COUNTS    520
#define WS_ZERO_ELEMS 30524
#define WS_OFFSETS   30524
#define WS_CURSOR    60528
#define WS_GAMMA     90528
#define WS_BETA      90784
#define WS_WLIN      91040
#define WS_BLIN      123808
#define WS_WGAT      123936
#define WS_ATT       156704
#define WS_BGAT      156960
#define WS_WP        157088
#define WS_BP        157600
#define WS_RW        157616
#define WS_SCALE     182192
#define WS_SHIFT     182448
#define WS_WC        182704
#define WS_BC        248240
#define WS_SD        248496
#define WS_SS        368496
#define WS_ONORM     488496
#define WS_CSR       668496
#define WS_XF        1178496
// U reuses the XF region (XF dead after k_gemm; U written after k_aggr)
#define WS_U         1178496
#define WS_BLKSUM    5018496
#define WS_BLKOFF    5018624
#define WS_Y         8858496
#define WS_XCG       16538496

#define OUT_LOSS_IDX 180000
#define OUT_FEAT_IDX 180001

#define SCAN_NB 118   // ceil(30000/256)

__device__ __forceinline__ float lrelu(float a) { return a >= 0.0f ? a : NEG_SLOPE * a; }

// ---- cross-lane helpers: DPP (VALU) for quad ops, immediate ds_swizzle for xor4/8/16 ----
template<int CTRL>
__device__ __forceinline__ float fdpp(float v) {
    return __int_as_float(__builtin_amdgcn_mov_dpp(__float_as_int(v), CTRL, 0xF, 0xF, true));
}
template<int PAT>
__device__ __forceinline__ float fswz(float v) {
    return __int_as_float(__builtin_amdgcn_ds_swizzle(__float_as_int(v), PAT));
}
// full reduce-broadcast over the lane's 32-lane group
__device__ __forceinline__ float redq(float v) {
    v += fdpp<0xB1>(v);        // xor 1 (quad_perm [1,0,3,2])
    v += fdpp<0x4E>(v);        // xor 2 (quad_perm [2,3,0,1])
    v += fswz<0x101F>(v);      // xor 4
    v += fswz<0x201F>(v);      // xor 8
    v += fswz<0x401F>(v);      // xor 16
    return v;
}
// 8-value packed reduce over 32-lane group, broadcast results to all lanes
__device__ __forceinline__ void dreduce(float dp[8], int k, float out[8]) {
    #pragma unroll
    for (int j = 0; j < 8; ++j) {
        dp[j] += fdpp<0xB1>(dp[j]);
        dp[j] += fdpp<0x4E>(dp[j]);
    }
    float A = (k == 0) ? dp[0] : (k == 1) ? dp[1] : (k == 2) ? dp[2] : dp[3];
    float B = (k == 0) ? dp[4] : (k == 1) ? dp[5] : (k == 2) ? dp[6] : dp[7];
    A += fswz<0x101F>(A); A += fswz<0x201F>(A); A += fswz<0x401F>(A);
    B += fswz<0x101F>(B); B += fswz<0x201F>(B); B += fswz<0x401F>(B);
    out[0] = fdpp<0x00>(A); out[1] = fdpp<0x55>(A); out[2] = fdpp<0xAA>(A); out[3] = fdpp<0xFF>(A);
    out[4] = fdpp<0x00>(B); out[5] = fdpp<0x55>(B); out[6] = fdpp<0xAA>(B); out[7] = fdpp<0xFF>(B);
}

// ---------- dtype detection: gamma is all-ones ----------
__global__ void k_detect(const unsigned int* gamma_raw, int* flag) {
    unsigned int w = gamma_raw[0];
    *flag = ((w & 0xFFFFu) == 0x3F80u) ? 1 : 0;   // bf16 pair 0x3F803F80 vs f32 0x3F800000
}

__device__ __forceinline__ float cvt_load(const void* p, int i, int f) {
    if (f) return __bfloat162float(((const __hip_bfloat16*)p)[i]);
    return ((const float*)p)[i];
}

__global__ void k_convert(const void* src, float* dst, int n, const int* flagp) {
    int f = *flagp;
    for (int i = blockIdx.x * blockDim.x + threadIdx.x; i < n; i += gridDim.x * blockDim.x)
        dst[i] = cvt_load(src, i, f);
}

// all small float params packed into ws params block
__global__ void k_convert_params(const void* p0, const void* p1, const void* p2, const void* p3,
                                 const void* p4, const void* p5, const void* p6, const void* p7,
                                 const void* p8, const void* p9, float* dst, const int* flagp) {
    int f = *flagp;
    int i = blockIdx.x * blockDim.x + threadIdx.x;
    if (i >= 91664) return;
    const void* p; int off;
    if      (i < 256)   { p = p0; off = i; }
    else if (i < 512)   { p = p1; off = i - 256; }
    else if (i < 33280) { p = p2; off = i - 512; }
    else if (i < 33408) { p = p3; off = i - 33280; }
    else if (i < 66176) { p = p4; off = i - 33408; }
    else if (i < 66432) { p = p5; off = i - 66176; }
    else if (i < 66560) { p = p6; off = i - 66432; }
    else if (i < 67072) { p = p7; off = i - 66560; }
    else if (i < 67088) { p = p8; off = i - 67072; }
    else                { p = p9; off = i - 67088; }
    dst[i] = cvt_load(p, off, f);
}

// ---------- batchnorm stats ----------
__global__ void k_bn_stats(const float* xf, float* bn_sum, float* bn_sq) {
    int t = threadIdx.x;                       // 256 threads, one feature each
    int rows = (NND + gridDim.x - 1) / gridDim.x;
    int r0 = blockIdx.x * rows;
    int r1 = min(NND, r0 + rows);
    float s = 0.0f, ss = 0.0f;
    for (int r = r0; r < r1; ++r) {
        float v = xf[(size_t)r * FD + t];
        s += v; ss += v * v;
    }
    atomicAdd(&bn_sum[t], s);
    atomicAdd(&bn_sq[t], ss);
}

__global__ void k_bn_final(const float* bn_sum, const float* bn_sq, const float* gamma,
                           const float* beta, float* scale, float* shift) {
    int t = threadIdx.x;
    float mean = bn_sum[t] / (float)NND;
    float var  = bn_sq[t] / (float)NND - mean * mean;
    float inv  = 1.0f / sqrtf(var + BN_EPS);
    float sc   = gamma[t] * inv;
    scale[t] = sc;
    shift[t] = beta[t] - mean * sc;
}

// fold BN into combined weight Wc[k][j] (j<128: lin, j>=128: gat) and bias bc
__global__ void k_fold(const float* wlin, const float* wgat, const float* blin,
                       const float* scale, const float* shift, float* Wc, float* bc) {
    int j = blockIdx.x;      // 0..255
    int k = threadIdx.x;     // 0..255
    float w = (j < 128) ? wlin[k * 128 + j] : wgat[k * 128 + (j - 128)];
    Wc[k * 256 + j] = scale[k] * w;
    __shared__ float red[256];
    red[k] = shift[k] * w;
    __syncthreads();
    for (int s = 128; s > 0; s >>= 1) { if (k < s) red[k] += red[k + s]; __syncthreads(); }
    if (k == 0) bc[j] = red[0] + (j < 128 ? blin[j] : 0.0f);
}

// ---------- GEMM: Y[N][256] = xf[N][256] @ Wc[256][256] + bc ----------
__global__ __launch_bounds__(256) void k_gemm(const float* A, const float* B,
                                              const float* bias, float* C) {
    __shared__ __align__(16) float As[16][128];
    __shared__ __align__(16) float Bs[16][64];
    int t  = threadIdx.x;
    int bm = blockIdx.x * 128;
    int bn = blockIdx.y * 64;
    int tr = t / 16, tc = t % 16;
    float acc[8][4] = {};
    int alm = t >> 2;           // 0..63
    int alk = (t & 3) * 4;      // k quad
    int blk = t >> 4;           // 0..15
    int bln = (t & 15) * 4;
    for (int k0 = 0; k0 < 256; k0 += 16) {
        #pragma unroll
        for (int half = 0; half < 2; ++half) {
            int row = bm + alm + half * 64;
            float4 av = make_float4(0.f, 0.f, 0.f, 0.f);
            if (row < NND) av = *(const float4*)(A + (size_t)row * 256 + k0 + alk);
            int m = alm + half * 64;
            As[alk + 0][m] = av.x; As[alk + 1][m] = av.y;
            As[alk + 2][m] = av.z; As[alk + 3][m] = av.w;
        }
        float4 bv = *(const float4*)(B + (size_t)(k0 + blk) * 256 + bn + bln);
        *(float4*)&Bs[blk][bln] = bv;
        __syncthreads();
        #pragma unroll
        for (int kk = 0; kk < 16; ++kk) {
            float a[8], b[4];
            *(float4*)&a[0] = *(const float4*)&As[kk][tr * 8];
            *(float4*)&a[4] = *(const float4*)&As[kk][tr * 8 + 4];
            *(float4*)&b[0] = *(const float4*)&Bs[kk][tc * 4];
            #pragma unroll
            for (int i = 0; i < 8; ++i)
                #pragma unroll
                for (int j = 0; j < 4; ++j) acc[i][j] += a[i] * b[j];
        }
        __syncthreads();
    }
    #pragma unroll
    for (int i = 0; i < 8; ++i) {
        int row = bm + tr * 8 + i;
        if (row < NND) {
            int col = bn + tc * 4;
            float4 o;
            o.x = acc[i][0] + bias[col + 0];
            o.y = acc[i][1] + bias[col + 1];
            o.z = acc[i][2] + bias[col + 2];
            o.w = acc[i][3] + bias[col + 3];
            *(float4*)(C + (size_t)row * 256 + col) = o;
        }
    }
}

// ---------- per-node attention scores ----------
__global__ void k_scores(const float* Y, const float* attf, float* sD, float* sS) {
    int idx = blockIdx.x * blockDim.x + threadIdx.x;
    if (idx >= NND * HEADS) return;
    int n = idx >> 2, h = idx & 3;
    const float* xrow = Y + (size_t)n * 256 + 128 + h * 32;
    const float* ai = attf + h * 64;
    const float* aj = ai + 32;
    float si = 0.f, sj = 0.f;
    #pragma unroll
    for (int k = 0; k < 32; ++k) { float v = xrow[k]; si += v * ai[k]; sj += v * aj[k]; }
    sD[idx] = si; sS[idx] = sj;
}

// ---------- CSR build ----------
__global__ void k_count(const int* ei, int* counts) {
    int e = blockIdx.x * blockDim.x + threadIdx.x;
    if (e >= NE + NND) return;
    int d = (e < NE) ? ei[NE + e] : (e - NE);
    atomicAdd(&counts[d], 1);
}

// hierarchical scan: block-local
__global__ void k_scan_blk(const int* counts, int* offsets, int* blksum) {
    int t = threadIdx.x, b = blockIdx.x;
    int i = b * 256 + t;
    int v = (i < NND) ? counts[i] : 0;
    int lane = t & 63, wv = t >> 6;
    int x = v;
    #pragma unroll
    for (int off = 1; off < 64; off <<= 1) {
        int y = __shfl_up(x, off);
        if (lane >= off) x += y;
    }
    __shared__ int wsum[4];
    if (lane == 63) wsum[wv] = x;
    __syncthreads();
    int add = 0;
    #pragma unroll
    for (int w = 0; w < 4; ++w) add += (w < wv) ? wsum[w] : 0;
    if (i < NND) offsets[i] = add + x - v;     // block-local exclusive
    if (t == 255) blksum[b] = add + x;
}

__global__ void k_scan_top(const int* blksum, int* blkoff) {
    int t = threadIdx.x;   // 128 threads, 2 waves
    int v = (t < SCAN_NB) ? blksum[t] : 0;
    int lane = t & 63, wv = t >> 6;
    int x = v;
    #pragma unroll
    for (int off = 1; off < 64; off <<= 1) {
        int y = __shfl_up(x, off);
        if (lane >= off) x += y;
    }
    __shared__ int ws2[2];
    if (lane == 63) ws2[wv] = x;
    __syncthreads();
    int add = (wv == 1) ? ws2[0] : 0;
    if (t < SCAN_NB) blkoff[t] = add + x - v;
}

__global__ void k_scan_add(const int* blkoff, int* offsets, int* cursor) {
    int i = blockIdx.x * 256 + threadIdx.x;
    if (i >= NND) return;
    int o = offsets[i] + blkoff[blockIdx.x];
    offsets[i] = o;
    cursor[i] = o;
}

__global__ void k_scatter(const int* ei, int* cursor, int* csr) {
    int e = blockIdx.x * blockDim.x + threadIdx.x;
    if (e >= NE + NND) return;
    int s, d;
    if (e < NE) { s = ei[e]; d = ei[NE + e]; } else { s = d = e - NE; }
    int pos = atomicAdd(&cursor[d], 1);
    csr[pos] = s;
}

// ---------- GAT aggregation: one wave per node ----------
__global__ __launch_bounds__(256) void k_aggr(const float* Y, const float* sD, const float* sS,
                                              const int* offsets, const int* counts, const int* csr,
                                              const float* bgat, float* xcg) {
    int wave = (blockIdx.x * blockDim.x + threadIdx.x) >> 6;
    int lane = threadIdx.x & 63;
    if (wave >= NND) return;
    int n = wave;
    int start = offsets[n], deg = counts[n];
    float4 sd = *(const float4*)(sD + (size_t)n * 4);
    // pass 1: per-head max
    float m0 = -1e30f, m1 = -1e30f, m2 = -1e30f, m3 = -1e30f;
    for (int e = lane; e < deg; e += 64) {
        int s = csr[start + e];
        float4 sj = *(const float4*)(sS + (size_t)s * 4);
        m0 = fmaxf(m0, lrelu(sd.x + sj.x));
        m1 = fmaxf(m1, lrelu(sd.y + sj.y));
        m2 = fmaxf(m2, lrelu(sd.z + sj.z));
        m3 = fmaxf(m3, lrelu(sd.w + sj.w));
    }
    #pragma unroll
    for (int off = 1; off < 64; off <<= 1) {
        m0 = fmaxf(m0, __shfl_xor(m0, off));
        m1 = fmaxf(m1, __shfl_xor(m1, off));
        m2 = fmaxf(m2, __shfl_xor(m2, off));
        m3 = fmaxf(m3, __shfl_xor(m3, off));
    }
    // pass 2: denominators
    float s0 = 0.f, s1 = 0.f, s2 = 0.f, s3 = 0.f;
    for (int e = lane; e < deg; e += 64) {
        int s = csr[start + e];
        float4 sj = *(const float4*)(sS + (size_t)s * 4);
        s0 += __expf(lrelu(sd.x + sj.x) - m0);
        s1 += __expf(lrelu(sd.y + sj.y) - m1);
        s2 += __expf(lrelu(sd.z + sj.z) - m2);
        s3 += __expf(lrelu(sd.w + sj.w) - m3);
    }
    #pragma unroll
    for (int off = 1; off < 64; off <<= 1) {
        s0 += __shfl_xor(s0, off); s1 += __shfl_xor(s1, off);
        s2 += __shfl_xor(s2, off); s3 += __shfl_xor(s3, off);
    }
    float i0 = 1.0f / (s0 + 1e-16f), i1 = 1.0f / (s1 + 1e-16f);
    float i2 = 1.0f / (s2 + 1e-16f), i3 = 1.0f / (s3 + 1e-16f);
    // pass 3: chunked — lane-parallel weight precompute, readlane broadcast, coalesced Y gather
    float acc0 = 0.f, acc1 = 0.f;
    int hA = lane >> 5;
    for (int base = 0; base < deg; base += 64) {
        int cnt = min(64, deg - base);
        int sidx = 0; float w0 = 0.f, w1 = 0.f, w2 = 0.f, w3 = 0.f;
        if (base + lane < deg) {
            sidx = csr[start + base + lane];
            float4 sj = *(const float4*)(sS + (size_t)sidx * 4);
            w0 = __expf(lrelu(sd.x + sj.x) - m0) * i0;
            w1 = __expf(lrelu(sd.y + sj.y) - m1) * i1;
            w2 = __expf(lrelu(sd.z + sj.z) - m2) * i2;
            w3 = __expf(lrelu(sd.w + sj.w) - m3) * i3;
        }
        for (int j = 0; j < cnt; ++j) {
            int s2i = __builtin_amdgcn_readlane(sidx, j);
            float wa0 = __int_as_float(__builtin_amdgcn_readlane(__float_as_int(w0), j));
            float wa1 = __int_as_float(__builtin_amdgcn_readlane(__float_as_int(w1), j));
            float wb0 = __int_as_float(__builtin_amdgcn_readlane(__float_as_int(w2), j));
            float wb1 = __int_as_float(__builtin_amdgcn_readlane(__float_as_int(w3), j));
            float wA = hA ? wa1 : wa0;
            float wB = hA ? wb1 : wb0;
            const float* xrow = Y + (size_t)s2i * 256 + 128;
            acc0 += wA * xrow[lane];
            acc1 += wB * xrow[64 + lane];
        }
    }
    float r0 = acc0 + bgat[lane];
    float r1 = acc1 + bgat[64 + lane];
    xcg[(size_t)n * 128 + lane]      = r0 > 0.f ? r0 : 0.f;
    xcg[(size_t)n * 128 + 64 + lane] = r1 > 0.f ? r1 : 0.f;
}

// ---------- primary caps: u[n][128], one wave per node, barrier-free ----------
__global__ __launch_bounds__(256, 4) void k_u(const float* Y, const float* xcg,
                                              const float* Wpf, const float* bpf, float* uG) {
    int lane = threadIdx.x & 63;
    int gw = blockIdx.x * 4 + (threadIdx.x >> 6);
    int nwaves = gridDim.x * 4;
    int r = lane >> 3, oo = lane & 7;
    float wpA[32], wpB[32];
    #pragma unroll
    for (int k = 0; k < 32; ++k) {
        wpA[k] = Wpf[k * 8 + oo];
        wpB[k] = Wpf[256 + k * 8 + oo];
    }
    float bpA = bpf[oo], bpB = bpf[8 + oo];
    for (int n = gw; n < NND; n += nwaves) {
        const float* rowp = (r < 4) ? (xcg + (size_t)n * 128 + r * 32)
                                    : (Y + (size_t)n * 256 + (r - 4) * 32);
        float pcA = bpA, pcB = bpB;
        #pragma unroll
        for (int k4 = 0; k4 < 8; ++k4) {
            float4 xv = *(const float4*)(rowp + k4 * 4);
            xv.x = fmaxf(xv.x, 0.f); xv.y = fmaxf(xv.y, 0.f);
            xv.z = fmaxf(xv.z, 0.f); xv.w = fmaxf(xv.w, 0.f);
            pcA += xv.x * wpA[k4*4+0] + xv.y * wpA[k4*4+1] + xv.z * wpA[k4*4+2] + xv.w * wpA[k4*4+3];
            pcB += xv.x * wpB[k4*4+0] + xv.y * wpB[k4*4+1] + xv.z * wpB[k4*4+2] + xv.w * wpB[k4*4+3];
        }
        float sA = pcA * pcA, sB = pcB * pcB;
        sA += fdpp<0xB1>(sA); sA += fdpp<0x4E>(sA); sA += fswz<0x101F>(sA);
        sB += fdpp<0xB1>(sB); sB += fdpp<0x4E>(sB); sB += fswz<0x101F>(sB);
        float cA = sqrtf(sA) / (1.0f + sA);
        float cB = sqrtf(sB) / (1.0f + sB);
        uG[(size_t)n * 128 + lane]      = pcA * cA;
        uG[(size_t)n * 128 + 64 + lane] = pcB * cB;
    }
}

// ---------- dynamic routing: one wave per (node, c), packed DPP/swizzle reductions ----------
__global__ __launch_bounds__(256, 3) void k_route3(const float* uG, const float* rwf,
                                                   float* onorm, void* dout, const int* flagp) {
    int flag = *flagp;
    int t = threadIdx.x;
    int lane = t & 63;
    int c = blockIdx.x % 6;                       // block-uniform c
    int wv = t >> 6;
    int widx = (blockIdx.x / 6) * 4 + wv;
    int nstep = (gridDim.x / 6) * 4;
    int h = lane >> 5, o = lane & 31;
    int k = lane & 3;
    // persistent route_w slice: rw[c][h*8+j][i][o]
    float rw[8][8];
    #pragma unroll
    for (int j = 0; j < 8; ++j)
        #pragma unroll
        for (int i = 0; i < 8; ++i)
            rw[j][i] = rwf[(((c * 16) + (h * 8 + j)) * 8 + i) * 32 + o];
    float* outf = (float*)dout;
    __hip_bfloat16* outb = (__hip_bfloat16*)dout;
    for (int n = widx; n < NND; n += nstep) {
        const float* up = uG + (size_t)n * 128 + h * 64;
        float p[8];
        #pragma unroll
        for (int j = 0; j < 8; ++j) {
            float4 a = *(const float4*)(up + j * 8);
            float4 b = *(const float4*)(up + j * 8 + 4);
            p[j] = a.x*rw[j][0] + a.y*rw[j][1] + a.z*rw[j][2] + a.w*rw[j][3]
                 + b.x*rw[j][4] + b.y*rw[j][5] + b.z*rw[j][6] + b.w*rw[j][7];
        }
        // ---- iter 1: probs = 1/16 exactly ----
        float tl = p[0]+p[1]+p[2]+p[3]+p[4]+p[5]+p[6]+p[7];
        float s = (tl + __shfl_xor(tl, 32)) * 0.0625f;
        float sq = redq(s * s);
        float v = s * (sqrtf(sq) / (1.0f + sq));
        float logits[8], dp[8];
        #pragma unroll
        for (int j = 0; j < 8; ++j) dp[j] = p[j] * v;
        dreduce(dp, k, logits);
        // ---- iters 2,3 ----
        float sq3 = 0.f, v3 = 0.f;
        #pragma unroll
        for (int it = 0; it < 2; ++it) {
            float mx = logits[0];
            #pragma unroll
            for (int j = 1; j < 8; ++j) mx = fmaxf(mx, logits[j]);
            mx = fmaxf(mx, __shfl_xor(mx, 32));
            float e[8]; float se = 0.f;
            #pragma unroll
            for (int j = 0; j < 8; ++j) { e[j] = __expf(logits[j] - mx); se += e[j]; }
            se += __shfl_xor(se, 32);
            float inv = 1.0f / se;
            float sl = 0.f;
            #pragma unroll
            for (int j = 0; j < 8; ++j) sl += e[j] * p[j];
            sl *= inv;
            float ss = sl + __shfl_xor(sl, 32);
            float q = redq(ss * ss);
            float vv = ss * (sqrtf(q) / (1.0f + q));
            if (it == 0) {
                float dd[8], lu[8];
                #pragma unroll
                for (int j = 0; j < 8; ++j) dd[j] = p[j] * vv;
                dreduce(dd, k, lu);
                #pragma unroll
                for (int j = 0; j < 8; ++j) logits[j] += lu[j];
            } else { v3 = vv; sq3 = q; }
        }
        // ---- output ----
        if (lane < 32) {
            size_t fidx = (size_t)OUT_FEAT_IDX + (size_t)n * 192 + c * 32 + o;
            if (flag) outb[fidx] = __float2bfloat16(v3); else outf[fidx] = v3;
            if (lane == 0) {
                float norm = sq3 / (1.0f + sq3);
                onorm[n * 6 + c] = norm;
                size_t oidx = (size_t)n * 6 + c;
                if (flag) outb[oidx] = __float2bfloat16(norm); else outf[oidx] = norm;
            }
        }
    }
}

// ---------- loss ----------
__global__ void k_loss(const float* onorm, const int* y, float* acc) {
    float l = 0.f;
    for (int n = blockIdx.x * blockDim.x + threadIdx.x; n < NND; n += gridDim.x * blockDim.x) {
        const float* v = onorm + n * 6;
        float m = v[0];
        #pragma unroll
        for (int cc = 1; cc < 6; ++cc) m = fmaxf(m, v[cc]);
        float s = 0.f;
        #pragma unroll
        for (int cc = 0; cc < 6; ++cc) s += expf(v[cc] - m);
        l += m + logf(s) - v[y[n]];
    }
    __shared__ float red[256];
    red[threadIdx.x] = l;
    __syncthreads();
    for (int s = 128; s > 0; s >>= 1) { if (threadIdx.x < s) red[threadIdx.x] += red[threadIdx.x + s]; __syncthreads(); }
    if (threadIdx.x == 0) atomicAdd(acc, red[0]);
}

__global__ void k_loss_fin(const float* acc, void* dout, const int* flagp) {
    float v = acc[0] / (float)NND;
    if (*flagp) ((__hip_bfloat16*)dout)[OUT_LOSS_IDX] = __float2bfloat16(v);
    else        ((float*)dout)[OUT_LOSS_IDX] = v;
}

extern "C" void kernel_launch(void* const* d_in, const int* in_sizes, int n_in,
                              void* d_out, int out_size, void* d_ws, size_t ws_size,
                              hipStream_t stream) {
    (void)in_sizes; (void)n_in; (void)out_size; (void)ws_size;
    float* ws = (float*)d_ws;
    int*  wsi = (int*)d_ws;
    const int* ei = (const int*)d_in[11];
    const int* y  = (const int*)d_in[12];

    hipMemsetAsync(d_ws, 0, (size_t)WS_ZERO_ELEMS * 4, stream);
    k_detect<<<1, 1, 0, stream>>>((const unsigned int*)d_in[1], wsi + WS_FLAG);

    k_convert<<<2048, 256, 0, stream>>>(d_in[0], ws + WS_XF, NND * FD, wsi + WS_FLAG);
    k_convert_params<<<(91664 + 255) / 256, 256, 0, stream>>>(
        d_in[1], d_in[2], d_in[3], d_in[4], d_in[5], d_in[6], d_in[7], d_in[8], d_in[9], d_in[10],
        ws + WS_GAMMA, wsi + WS_FLAG);

    k_bn_stats<<<120, 256, 0, stream>>>(ws + WS_XF, ws + WS_BNSUM, ws + WS_BNSQ);
    k_bn_final<<<1, 256, 0, stream>>>(ws + WS_BNSUM, ws + WS_BNSQ, ws + WS_GAMMA, ws + WS_BETA,
                                      ws + WS_SCALE, ws + WS_SHIFT);
    k_fold<<<256, 256, 0, stream>>>(ws + WS_WLIN, ws + WS_WGAT, ws + WS_BLIN,
                                    ws + WS_SCALE, ws + WS_SHIFT, ws + WS_WC, ws + WS_BC);

    k_gemm<<<dim3((NND + 127) / 128, 4), 256, 0, stream>>>(ws + WS_XF, ws + WS_WC, ws + WS_BC, ws + WS_Y);

    k_scores<<<(NND * HEADS + 255) / 256, 256, 0, stream>>>(ws + WS_Y, ws + WS_ATT, ws + WS_SD, ws + WS_SS);

    k_count<<<(NE + NND + 255) / 256, 256, 0, stream>>>(ei, wsi + WS_COUNTS);
    k_scan_blk<<<SCAN_NB, 256, 0, stream>>>(wsi + WS_COUNTS, wsi + WS_OFFSETS, wsi + WS_BLKSUM);
    k_scan_top<<<1, 128, 0, stream>>>(wsi + WS_BLKSUM, wsi + WS_BLKOFF);
    k_scan_add<<<SCAN_NB, 256, 0, stream>>>(wsi + WS_BLKOFF, wsi + WS_OFFSETS, wsi + WS_CURSOR);
    k_scatter<<<(NE + NND + 255) / 256, 256, 0, stream>>>(ei, wsi + WS_CURSOR, wsi + WS_CSR);

    k_aggr<<<(NND + 3) / 4, 256, 0, stream>>>(ws + WS_Y, ws + WS_SD, ws + WS_SS,
                                              wsi + WS_OFFSETS, wsi + WS_COUNTS, wsi + WS_CSR,
                                              ws + WS_BGAT, ws + WS_XCG);

    k_u<<<512, 256, 0, stream>>>(ws + WS_Y, ws + WS_XCG, ws + WS_WP, ws + WS_BP, ws + WS_U);
    k_route3<<<3072, 256, 0, stream>>>(ws + WS_U, ws + WS_RW, ws + WS_ONORM, d_out, wsi + WS_FLAG);

    k_loss<<<118, 256, 0, stream>>>(ws + WS_ONORM, y, ws + WS_LOSS);
    k_loss_fin<<<1, 1, 0, stream>>>(ws + WS_LOSS, d_out, wsi + WS_FLAG);
}

// Round 4
// 543.493 us; speedup vs baseline: 1.4601x; 1.0182x over previous
//
#include <hip/hip_runtime.h>
#include <hip/hip_bf16.h>

#define NND 30000
#define NE  480000
#define FD  256
#define HD  32
#define HEADS 4
#define NLAB 6
#define NEG_SLOPE 0.2f
#define BN_EPS 1e-5f

// ---- workspace layout (offsets in 4-byte elements) ----
#define WS_FLAG      0
#define WS_BNSUM     4
#define WS_BNSQ      260
#define WS_LOSS      516
#define WS_COUNTS    520
#define WS_ZERO_ELEMS 30524
#define WS_OFFSETS   30524
#define WS_CURSOR    60528
#define WS_GAMMA     90528
#define WS_BETA      90784
#define WS_WLIN      91040
#define WS_BLIN      123808
#define WS_WGAT      123936
#define WS_ATT       156704
#define WS_BGAT      156960
#define WS_WP        157088
#define WS_BP        157600
#define WS_RW        157616
#define WS_SCALE     182192
#define WS_SHIFT     182448
#define WS_WC        182704
#define WS_BC        248240
#define WS_SD        248496
#define WS_SS        368496
#define WS_ONORM     488496
#define WS_CSR       668496
#define WS_XF        1178496
// U reuses the XF region (XF dead after k_gemm; U written after k_aggr)
#define WS_U         1178496
#define WS_BLKSUM    5018496
#define WS_BLKOFF    5018624
#define WS_Y         8858496
#define WS_XCG       16538496

#define OUT_LOSS_IDX 180000
#define OUT_FEAT_IDX 180001

#define SCAN_NB 118   // ceil(30000/256)

__device__ __forceinline__ float lrelu(float a) { return a >= 0.0f ? a : NEG_SLOPE * a; }

// opaque touch: forces the value to be materialized in a VGPR and kept live
// (an asm result cannot be rematerialized by reloading from memory)
__device__ __forceinline__ void pin(float& x) { asm volatile("" : "+v"(x)); }

// ---- cross-lane helpers: DPP (VALU) for quad ops, immediate ds_swizzle for xor4/8/16 ----
template<int CTRL>
__device__ __forceinline__ float fdpp(float v) {
    return __int_as_float(__builtin_amdgcn_mov_dpp(__float_as_int(v), CTRL, 0xF, 0xF, true));
}
template<int PAT>
__device__ __forceinline__ float fswz(float v) {
    return __int_as_float(__builtin_amdgcn_ds_swizzle(__float_as_int(v), PAT));
}
// full reduce-broadcast over the lane's 32-lane group
__device__ __forceinline__ float redq(float v) {
    v += fdpp<0xB1>(v);        // xor 1 (quad_perm [1,0,3,2])
    v += fdpp<0x4E>(v);        // xor 2 (quad_perm [2,3,0,1])
    v += fswz<0x101F>(v);      // xor 4
    v += fswz<0x201F>(v);      // xor 8
    v += fswz<0x401F>(v);      // xor 16
    return v;
}
__device__ __forceinline__ float redq_sum64(float v) {
    v = redq(v);
    return v + __shfl_xor(v, 32);
}
__device__ __forceinline__ float redq_max64(float v) {
    v = fmaxf(v, fdpp<0xB1>(v));
    v = fmaxf(v, fdpp<0x4E>(v));
    v = fmaxf(v, fswz<0x101F>(v));
    v = fmaxf(v, fswz<0x201F>(v));
    v = fmaxf(v, fswz<0x401F>(v));
    return fmaxf(v, __shfl_xor(v, 32));
}
// 8-value packed reduce over 32-lane group, broadcast results to all lanes
__device__ __forceinline__ void dreduce(float dp[8], int k, float out[8]) {
    #pragma unroll
    for (int j = 0; j < 8; ++j) {
        dp[j] += fdpp<0xB1>(dp[j]);
        dp[j] += fdpp<0x4E>(dp[j]);
    }
    float A = (k == 0) ? dp[0] : (k == 1) ? dp[1] : (k == 2) ? dp[2] : dp[3];
    float B = (k == 0) ? dp[4] : (k == 1) ? dp[5] : (k == 2) ? dp[6] : dp[7];
    A += fswz<0x101F>(A); A += fswz<0x201F>(A); A += fswz<0x401F>(A);
    B += fswz<0x101F>(B); B += fswz<0x201F>(B); B += fswz<0x401F>(B);
    out[0] = fdpp<0x00>(A); out[1] = fdpp<0x55>(A); out[2] = fdpp<0xAA>(A); out[3] = fdpp<0xFF>(A);
    out[4] = fdpp<0x00>(B); out[5] = fdpp<0x55>(B); out[6] = fdpp<0xAA>(B); out[7] = fdpp<0xFF>(B);
}

// ---------- dtype detection: gamma is all-ones ----------
__global__ void k_detect(const unsigned int* gamma_raw, int* flag) {
    unsigned int w = gamma_raw[0];
    *flag = ((w & 0xFFFFu) == 0x3F80u) ? 1 : 0;   // bf16 pair 0x3F803F80 vs f32 0x3F800000
}

__device__ __forceinline__ float cvt_load(const void* p, int i, int f) {
    if (f) return __bfloat162float(((const __hip_bfloat16*)p)[i]);
    return ((const float*)p)[i];
}

__global__ void k_convert(const void* src, float* dst, int n, const int* flagp) {
    int f = *flagp;
    for (int i = blockIdx.x * blockDim.x + threadIdx.x; i < n; i += gridDim.x * blockDim.x)
        dst[i] = cvt_load(src, i, f);
}

// all small float params packed into ws params block
__global__ void k_convert_params(const void* p0, const void* p1, const void* p2, const void* p3,
                                 const void* p4, const void* p5, const void* p6, const void* p7,
                                 const void* p8, const void* p9, float* dst, const int* flagp) {
    int f = *flagp;
    int i = blockIdx.x * blockDim.x + threadIdx.x;
    if (i >= 91664) return;
    const void* p; int off;
    if      (i < 256)   { p = p0; off = i; }
    else if (i < 512)   { p = p1; off = i - 256; }
    else if (i < 33280) { p = p2; off = i - 512; }
    else if (i < 33408) { p = p3; off = i - 33280; }
    else if (i < 66176) { p = p4; off = i - 33408; }
    else if (i < 66432) { p = p5; off = i - 66176; }
    else if (i < 66560) { p = p6; off = i - 66432; }
    else if (i < 67072) { p = p7; off = i - 66560; }
    else if (i < 67088) { p = p8; off = i - 67072; }
    else                { p = p9; off = i - 67088; }
    dst[i] = cvt_load(p, off, f);
}

// ---------- batchnorm stats ----------
__global__ void k_bn_stats(const float* xf, float* bn_sum, float* bn_sq) {
    int t = threadIdx.x;                       // 256 threads, one feature each
    int rows = (NND + gridDim.x - 1) / gridDim.x;
    int r0 = blockIdx.x * rows;
    int r1 = min(NND, r0 + rows);
    float s = 0.0f, ss = 0.0f;
    for (int r = r0; r < r1; ++r) {
        float v = xf[(size_t)r * FD + t];
        s += v; ss += v * v;
    }
    atomicAdd(&bn_sum[t], s);
    atomicAdd(&bn_sq[t], ss);
}

__global__ void k_bn_final(const float* bn_sum, const float* bn_sq, const float* gamma,
                           const float* beta, float* scale, float* shift) {
    int t = threadIdx.x;
    float mean = bn_sum[t] / (float)NND;
    float var  = bn_sq[t] / (float)NND - mean * mean;
    float inv  = 1.0f / sqrtf(var + BN_EPS);
    float sc   = gamma[t] * inv;
    scale[t] = sc;
    shift[t] = beta[t] - mean * sc;
}

// fold BN into combined weight Wc[k][j] (j<128: lin, j>=128: gat) and bias bc
__global__ void k_fold(const float* wlin, const float* wgat, const float* blin,
                       const float* scale, const float* shift, float* Wc, float* bc) {
    int j = blockIdx.x;      // 0..255
    int k = threadIdx.x;     // 0..255
    float w = (j < 128) ? wlin[k * 128 + j] : wgat[k * 128 + (j - 128)];
    Wc[k * 256 + j] = scale[k] * w;
    __shared__ float red[256];
    red[k] = shift[k] * w;
    __syncthreads();
    for (int s = 128; s > 0; s >>= 1) { if (k < s) red[k] += red[k + s]; __syncthreads(); }
    if (k == 0) bc[j] = red[0] + (j < 128 ? blin[j] : 0.0f);
}

// ---------- GEMM: Y[N][256] = xf[N][256] @ Wc[256][256] + bc ----------
__global__ __launch_bounds__(256) void k_gemm(const float* A, const float* B,
                                              const float* bias, float* C) {
    __shared__ __align__(16) float As[16][128];
    __shared__ __align__(16) float Bs[16][64];
    int t  = threadIdx.x;
    int bm = blockIdx.x * 128;
    int bn = blockIdx.y * 64;
    int tr = t / 16, tc = t % 16;
    float acc[8][4] = {};
    int alm = t >> 2;           // 0..63
    int alk = (t & 3) * 4;      // k quad
    int blk = t >> 4;           // 0..15
    int bln = (t & 15) * 4;
    for (int k0 = 0; k0 < 256; k0 += 16) {
        #pragma unroll
        for (int half = 0; half < 2; ++half) {
            int row = bm + alm + half * 64;
            float4 av = make_float4(0.f, 0.f, 0.f, 0.f);
            if (row < NND) av = *(const float4*)(A + (size_t)row * 256 + k0 + alk);
            int m = alm + half * 64;
            As[alk + 0][m] = av.x; As[alk + 1][m] = av.y;
            As[alk + 2][m] = av.z; As[alk + 3][m] = av.w;
        }
        float4 bv = *(const float4*)(B + (size_t)(k0 + blk) * 256 + bn + bln);
        *(float4*)&Bs[blk][bln] = bv;
        __syncthreads();
        #pragma unroll
        for (int kk = 0; kk < 16; ++kk) {
            float a[8], b[4];
            *(float4*)&a[0] = *(const float4*)&As[kk][tr * 8];
            *(float4*)&a[4] = *(const float4*)&As[kk][tr * 8 + 4];
            *(float4*)&b[0] = *(const float4*)&Bs[kk][tc * 4];
            #pragma unroll
            for (int i = 0; i < 8; ++i)
                #pragma unroll
                for (int j = 0; j < 4; ++j) acc[i][j] += a[i] * b[j];
        }
        __syncthreads();
    }
    #pragma unroll
    for (int i = 0; i < 8; ++i) {
        int row = bm + tr * 8 + i;
        if (row < NND) {
            int col = bn + tc * 4;
            float4 o;
            o.x = acc[i][0] + bias[col + 0];
            o.y = acc[i][1] + bias[col + 1];
            o.z = acc[i][2] + bias[col + 2];
            o.w = acc[i][3] + bias[col + 3];
            *(float4*)(C + (size_t)row * 256 + col) = o;
        }
    }
}

// ---------- per-node attention scores ----------
__global__ void k_scores(const float* Y, const float* attf, float* sD, float* sS) {
    int idx = blockIdx.x * blockDim.x + threadIdx.x;
    if (idx >= NND * HEADS) return;
    int n = idx >> 2, h = idx & 3;
    const float* xrow = Y + (size_t)n * 256 + 128 + h * 32;
    const float* ai = attf + h * 64;
    const float* aj = ai + 32;
    float si = 0.f, sj = 0.f;
    #pragma unroll
    for (int k = 0; k < 32; ++k) { float v = xrow[k]; si += v * ai[k]; sj += v * aj[k]; }
    sD[idx] = si; sS[idx] = sj;
}

// ---------- CSR build ----------
__global__ void k_count(const int* ei, int* counts) {
    int e = blockIdx.x * blockDim.x + threadIdx.x;
    if (e >= NE + NND) return;
    int d = (e < NE) ? ei[NE + e] : (e - NE);
    atomicAdd(&counts[d], 1);
}

// hierarchical scan: block-local
__global__ void k_scan_blk(const int* counts, int* offsets, int* blksum) {
    int t = threadIdx.x, b = blockIdx.x;
    int i = b * 256 + t;
    int v = (i < NND) ? counts[i] : 0;
    int lane = t & 63, wv = t >> 6;
    int x = v;
    #pragma unroll
    for (int off = 1; off < 64; off <<= 1) {
        int y = __shfl_up(x, off);
        if (lane >= off) x += y;
    }
    __shared__ int wsum[4];
    if (lane == 63) wsum[wv] = x;
    __syncthreads();
    int add = 0;
    #pragma unroll
    for (int w = 0; w < 4; ++w) add += (w < wv) ? wsum[w] : 0;
    if (i < NND) offsets[i] = add + x - v;     // block-local exclusive
    if (t == 255) blksum[b] = add + x;
}

__global__ void k_scan_top(const int* blksum, int* blkoff) {
    int t = threadIdx.x;   // 128 threads, 2 waves
    int v = (t < SCAN_NB) ? blksum[t] : 0;
    int lane = t & 63, wv = t >> 6;
    int x = v;
    #pragma unroll
    for (int off = 1; off < 64; off <<= 1) {
        int y = __shfl_up(x, off);
        if (lane >= off) x += y;
    }
    __shared__ int ws2[2];
    if (lane == 63) ws2[wv] = x;
    __syncthreads();
    int add = (wv == 1) ? ws2[0] : 0;
    if (t < SCAN_NB) blkoff[t] = add + x - v;
}

__global__ void k_scan_add(const int* blkoff, int* offsets, int* cursor) {
    int i = blockIdx.x * 256 + threadIdx.x;
    if (i >= NND) return;
    int o = offsets[i] + blkoff[blockIdx.x];
    offsets[i] = o;
    cursor[i] = o;
}

__global__ void k_scatter(const int* ei, int* cursor, int* csr) {
    int e = blockIdx.x * blockDim.x + threadIdx.x;
    if (e >= NE + NND) return;
    int s, d;
    if (e < NE) { s = ei[e]; d = ei[NE + e]; } else { s = d = e - NE; }
    int pos = atomicAdd(&cursor[d], 1);
    csr[pos] = s;
}

// ---------- GAT aggregation: one wave per node ----------
__global__ __launch_bounds__(256) void k_aggr(const float* Y, const float* sD, const float* sS,
                                              const int* offsets, const int* counts, const int* csr,
                                              const float* bgat, float* xcg) {
    int wave = (blockIdx.x * blockDim.x + threadIdx.x) >> 6;
    int lane = threadIdx.x & 63;
    if (wave >= NND) return;
    int n = wave;
    int start = offsets[n], deg = counts[n];
    float4 sd = *(const float4*)(sD + (size_t)n * 4);
    // pass 1: per-head max
    float m0 = -1e30f, m1 = -1e30f, m2 = -1e30f, m3 = -1e30f;
    for (int e = lane; e < deg; e += 64) {
        int s = csr[start + e];
        float4 sj = *(const float4*)(sS + (size_t)s * 4);
        m0 = fmaxf(m0, lrelu(sd.x + sj.x));
        m1 = fmaxf(m1, lrelu(sd.y + sj.y));
        m2 = fmaxf(m2, lrelu(sd.z + sj.z));
        m3 = fmaxf(m3, lrelu(sd.w + sj.w));
    }
    m0 = redq_max64(m0); m1 = redq_max64(m1);
    m2 = redq_max64(m2); m3 = redq_max64(m3);
    // pass 2: denominators
    float s0 = 0.f, s1 = 0.f, s2 = 0.f, s3 = 0.f;
    for (int e = lane; e < deg; e += 64) {
        int s = csr[start + e];
        float4 sj = *(const float4*)(sS + (size_t)s * 4);
        s0 += __expf(lrelu(sd.x + sj.x) - m0);
        s1 += __expf(lrelu(sd.y + sj.y) - m1);
        s2 += __expf(lrelu(sd.z + sj.z) - m2);
        s3 += __expf(lrelu(sd.w + sj.w) - m3);
    }
    s0 = redq_sum64(s0); s1 = redq_sum64(s1);
    s2 = redq_sum64(s2); s3 = redq_sum64(s3);
    float i0 = 1.0f / (s0 + 1e-16f), i1 = 1.0f / (s1 + 1e-16f);
    float i2 = 1.0f / (s2 + 1e-16f), i3 = 1.0f / (s3 + 1e-16f);
    // pass 3: chunked — lane-parallel weight precompute, readlane broadcast, coalesced Y gather
    float acc0 = 0.f, acc1 = 0.f;
    int hA = lane >> 5;
    for (int base = 0; base < deg; base += 64) {
        int cnt = min(64, deg - base);
        int sidx = 0; float w0 = 0.f, w1 = 0.f, w2 = 0.f, w3 = 0.f;
        if (base + lane < deg) {
            sidx = csr[start + base + lane];
            float4 sj = *(const float4*)(sS + (size_t)sidx * 4);
            w0 = __expf(lrelu(sd.x + sj.x) - m0) * i0;
            w1 = __expf(lrelu(sd.y + sj.y) - m1) * i1;
            w2 = __expf(lrelu(sd.z + sj.z) - m2) * i2;
            w3 = __expf(lrelu(sd.w + sj.w) - m3) * i3;
        }
        for (int j = 0; j < cnt; ++j) {
            int s2i = __builtin_amdgcn_readlane(sidx, j);
            float wa0 = __int_as_float(__builtin_amdgcn_readlane(__float_as_int(w0), j));
            float wa1 = __int_as_float(__builtin_amdgcn_readlane(__float_as_int(w1), j));
            float wb0 = __int_as_float(__builtin_amdgcn_readlane(__float_as_int(w2), j));
            float wb1 = __int_as_float(__builtin_amdgcn_readlane(__float_as_int(w3), j));
            float wA = hA ? wa1 : wa0;
            float wB = hA ? wb1 : wb0;
            const float* xrow = Y + (size_t)s2i * 256 + 128;
            acc0 += wA * xrow[lane];
            acc1 += wB * xrow[64 + lane];
        }
    }
    float r0 = acc0 + bgat[lane];
    float r1 = acc1 + bgat[64 + lane];
    xcg[(size_t)n * 128 + lane]      = r0 > 0.f ? r0 : 0.f;
    xcg[(size_t)n * 128 + 64 + lane] = r1 > 0.f ? r1 : 0.f;
}

// ---------- primary caps: u[n][128], one wave per node, barrier-free ----------
__global__ __launch_bounds__(256, 4) void k_u(const float* Y, const float* xcg,
                                              const float* Wpf, const float* bpf, float* uG) {
    int lane = threadIdx.x & 63;
    int gw = blockIdx.x * 4 + (threadIdx.x >> 6);
    int nwaves = gridDim.x * 4;
    int r = lane >> 3, oo = lane & 7;
    float wpA[32], wpB[32];
    #pragma unroll
    for (int k = 0; k < 32; ++k) {
        wpA[k] = Wpf[k * 8 + oo];
        wpB[k] = Wpf[256 + k * 8 + oo];
    }
    #pragma unroll
    for (int k = 0; k < 32; ++k) { pin(wpA[k]); pin(wpB[k]); }
    float bpA = bpf[oo], bpB = bpf[8 + oo];
    for (int n = gw; n < NND; n += nwaves) {
        const float* rowp = (r < 4) ? (xcg + (size_t)n * 128 + r * 32)
                                    : (Y + (size_t)n * 256 + (r - 4) * 32);
        float pcA = bpA, pcB = bpB;
        #pragma unroll
        for (int k4 = 0; k4 < 8; ++k4) {
            float4 xv = *(const float4*)(rowp + k4 * 4);
            xv.x = fmaxf(xv.x, 0.f); xv.y = fmaxf(xv.y, 0.f);
            xv.z = fmaxf(xv.z, 0.f); xv.w = fmaxf(xv.w, 0.f);
            pcA += xv.x * wpA[k4*4+0] + xv.y * wpA[k4*4+1] + xv.z * wpA[k4*4+2] + xv.w * wpA[k4*4+3];
            pcB += xv.x * wpB[k4*4+0] + xv.y * wpB[k4*4+1] + xv.z * wpB[k4*4+2] + xv.w * wpB[k4*4+3];
        }
        float sA = pcA * pcA, sB = pcB * pcB;
        sA += fdpp<0xB1>(sA); sA += fdpp<0x4E>(sA); sA += fswz<0x101F>(sA);
        sB += fdpp<0xB1>(sB); sB += fdpp<0x4E>(sB); sB += fswz<0x101F>(sB);
        float cA = sqrtf(sA) / (1.0f + sA);
        float cB = sqrtf(sB) / (1.0f + sB);
        uG[(size_t)n * 128 + lane]      = pcA * cA;
        uG[(size_t)n * 128 + 64 + lane] = pcB * cB;
    }
}

// ---------- dynamic routing: one wave per (node, c), packed DPP/swizzle reductions ----------
__global__ __launch_bounds__(256, 3) void k_route3(const float* uG, const float* rwf,
                                                   float* onorm, void* dout, const int* flagp) {
    int flag = *flagp;
    int t = threadIdx.x;
    int lane = t & 63;
    int c = blockIdx.x % 6;                       // block-uniform c
    int wv = t >> 6;
    int widx = (blockIdx.x / 6) * 4 + wv;
    int nstep = (gridDim.x / 6) * 4;
    int h = lane >> 5, o = lane & 31;
    int k = lane & 3;
    // persistent route_w slice: rw[c][h*8+j][i][o] — pinned in VGPRs (no remat)
    float rw[8][8];
    #pragma unroll
    for (int j = 0; j < 8; ++j)
        #pragma unroll
        for (int i = 0; i < 8; ++i)
            rw[j][i] = rwf[(((c * 16) + (h * 8 + j)) * 8 + i) * 32 + o];
    #pragma unroll
    for (int j = 0; j < 8; ++j)
        #pragma unroll
        for (int i = 0; i < 8; ++i)
            pin(rw[j][i]);
    float* outf = (float*)dout;
    __hip_bfloat16* outb = (__hip_bfloat16*)dout;
    for (int n = widx; n < NND; n += nstep) {
        const float* up = uG + (size_t)n * 128 + h * 64;
        float p[8];
        #pragma unroll
        for (int j = 0; j < 8; ++j) {
            float4 a = *(const float4*)(up + j * 8);
            float4 b = *(const float4*)(up + j * 8 + 4);
            p[j] = a.x*rw[j][0] + a.y*rw[j][1] + a.z*rw[j][2] + a.w*rw[j][3]
                 + b.x*rw[j][4] + b.y*rw[j][5] + b.z*rw[j][6] + b.w*rw[j][7];
        }
        // ---- iter 1: probs = 1/16 exactly ----
        float tl = p[0]+p[1]+p[2]+p[3]+p[4]+p[5]+p[6]+p[7];
        float s = (tl + __shfl_xor(tl, 32)) * 0.0625f;
        float sq = redq(s * s);
        float v = s * (sqrtf(sq) / (1.0f + sq));
        float logits[8], dp[8];
        #pragma unroll
        for (int j = 0; j < 8; ++j) dp[j] = p[j] * v;
        dreduce(dp, k, logits);
        // ---- iters 2,3 ----
        float sq3 = 0.f, v3 = 0.f;
        #pragma unroll
        for (int it = 0; it < 2; ++it) {
            float mx = logits[0];
            #pragma unroll
            for (int j = 1; j < 8; ++j) mx = fmaxf(mx, logits[j]);
            mx = fmaxf(mx, __shfl_xor(mx, 32));
            float e[8]; float se = 0.f;
            #pragma unroll
            for (int j = 0; j < 8; ++j) { e[j] = __expf(logits[j] - mx); se += e[j]; }
            se += __shfl_xor(se, 32);
            float inv = 1.0f / se;
            float sl = 0.f;
            #pragma unroll
            for (int j = 0; j < 8; ++j) sl += e[j] * p[j];
            sl *= inv;
            float ss = sl + __shfl_xor(sl, 32);
            float q = redq(ss * ss);
            float vv = ss * (sqrtf(q) / (1.0f + q));
            if (it == 0) {
                float dd[8], lu[8];
                #pragma unroll
                for (int j = 0; j < 8; ++j) dd[j] = p[j] * vv;
                dreduce(dd, k, lu);
                #pragma unroll
                for (int j = 0; j < 8; ++j) logits[j] += lu[j];
            } else { v3 = vv; sq3 = q; }
        }
        // ---- output ----
        if (lane < 32) {
            size_t fidx = (size_t)OUT_FEAT_IDX + (size_t)n * 192 + c * 32 + o;
            if (flag) outb[fidx] = __float2bfloat16(v3); else outf[fidx] = v3;
            if (lane == 0) {
                float norm = sq3 / (1.0f + sq3);
                onorm[n * 6 + c] = norm;
                size_t oidx = (size_t)n * 6 + c;
                if (flag) outb[oidx] = __float2bfloat16(norm); else outf[oidx] = norm;
            }
        }
    }
}

// ---------- loss ----------
__global__ void k_loss(const float* onorm, const int* y, float* acc) {
    float l = 0.f;
    for (int n = blockIdx.x * blockDim.x + threadIdx.x; n < NND; n += gridDim.x * blockDim.x) {
        const float* v = onorm + n * 6;
        float m = v[0];
        #pragma unroll
        for (int cc = 1; cc < 6; ++cc) m = fmaxf(m, v[cc]);
        float s = 0.f;
        #pragma unroll
        for (int cc = 0; cc < 6; ++cc) s += expf(v[cc] - m);
        l += m + logf(s) - v[y[n]];
    }
    __shared__ float red[256];
    red[threadIdx.x] = l;
    __syncthreads();
    for (int s = 128; s > 0; s >>= 1) { if (threadIdx.x < s) red[threadIdx.x] += red[threadIdx.x + s]; __syncthreads(); }
    if (threadIdx.x == 0) atomicAdd(acc, red[0]);
}

__global__ void k_loss_fin(const float* acc, void* dout, const int* flagp) {
    float v = acc[0] / (float)NND;
    if (*flagp) ((__hip_bfloat16*)dout)[OUT_LOSS_IDX] = __float2bfloat16(v);
    else        ((float*)dout)[OUT_LOSS_IDX] = v;
}

extern "C" void kernel_launch(void* const* d_in, const int* in_sizes, int n_in,
                              void* d_out, int out_size, void* d_ws, size_t ws_size,
                              hipStream_t stream) {
    (void)in_sizes; (void)n_in; (void)out_size; (void)ws_size;
    float* ws = (float*)d_ws;
    int*  wsi = (int*)d_ws;
    const int* ei = (const int*)d_in[11];
    const int* y  = (const int*)d_in[12];

    hipMemsetAsync(d_ws, 0, (size_t)WS_ZERO_ELEMS * 4, stream);
    k_detect<<<1, 1, 0, stream>>>((const unsigned int*)d_in[1], wsi + WS_FLAG);

    k_convert<<<2048, 256, 0, stream>>>(d_in[0], ws + WS_XF, NND * FD, wsi + WS_FLAG);
    k_convert_params<<<(91664 + 255) / 256, 256, 0, stream>>>(
        d_in[1], d_in[2], d_in[3], d_in[4], d_in[5], d_in[6], d_in[7], d_in[8], d_in[9], d_in[10],
        ws + WS_GAMMA, wsi + WS_FLAG);

    k_bn_stats<<<120, 256, 0, stream>>>(ws + WS_XF, ws + WS_BNSUM, ws + WS_BNSQ);
    k_bn_final<<<1, 256, 0, stream>>>(ws + WS_BNSUM, ws + WS_BNSQ, ws + WS_GAMMA, ws + WS_BETA,
                                      ws + WS_SCALE, ws + WS_SHIFT);
    k_fold<<<256, 256, 0, stream>>>(ws + WS_WLIN, ws + WS_WGAT, ws + WS_BLIN,
                                    ws + WS_SCALE, ws + WS_SHIFT, ws + WS_WC, ws + WS_BC);

    k_gemm<<<dim3((NND + 127) / 128, 4), 256, 0, stream>>>(ws + WS_XF, ws + WS_WC, ws + WS_BC, ws + WS_Y);

    k_scores<<<(NND * HEADS + 255) / 256, 256, 0, stream>>>(ws + WS_Y, ws + WS_ATT, ws + WS_SD, ws + WS_SS);

    k_count<<<(NE + NND + 255) / 256, 256, 0, stream>>>(ei, wsi + WS_COUNTS);
    k_scan_blk<<<SCAN_NB, 256, 0, stream>>>(wsi + WS_COUNTS, wsi + WS_OFFSETS, wsi + WS_BLKSUM);
    k_scan_top<<<1, 128, 0, stream>>>(wsi + WS_BLKSUM, wsi + WS_BLKOFF);
    k_scan_add<<<SCAN_NB, 256, 0, stream>>>(wsi + WS_BLKOFF, wsi + WS_OFFSETS, wsi + WS_CURSOR);
    k_scatter<<<(NE + NND + 255) / 256, 256, 0, stream>>>(ei, wsi + WS_CURSOR, wsi + WS_CSR);

    k_aggr<<<(NND + 3) / 4, 256, 0, stream>>>(ws + WS_Y, ws + WS_SD, ws + WS_SS,
                                              wsi + WS_OFFSETS, wsi + WS_COUNTS, wsi + WS_CSR,
                                              ws + WS_BGAT, ws + WS_XCG);

    k_u<<<512, 256, 0, stream>>>(ws + WS_Y, ws + WS_XCG, ws + WS_WP, ws + WS_BP, ws + WS_U);
    k_route3<<<3072, 256, 0, stream>>>(ws + WS_U, ws + WS_RW, ws + WS_ONORM, d_out, wsi + WS_FLAG);

    k_loss<<<118, 256, 0, stream>>>(ws + WS_ONORM, y, ws + WS_LOSS);
    k_loss_fin<<<1, 1, 0, stream>>>(ws + WS_LOSS, d_out, wsi + WS_FLAG);
}